// Round 6
// baseline (955.764 us; speedup 1.0000x reference)
//
#include <hip/hip_runtime.h>
#include <cstdint>
#include <cstddef>

// AnimaMLP: router(top-5 of 8, softmax/e) + 8 dense experts (silu(xWg)*xWu)Wd,
// signed-weighted sum, plus mean(output^2) scalar.
//
// Expert-chunked 8-phase plan (round-1 ws footprint, 201.6MB):
//   pass p in {0,1}: experts 4p..4p+3
//     gemm1_8p (1024 blocks, round-4 form): H'[8192 x 4096]
//     gemm2_8p (read-ahead pipelined): out (+)= H' @ Wdt[:, 4096p..]
// ws map (bytes):
//   0         Xb   bf16 8192x2048   33,554,432
//   33554432  Wgt  bf16 8x1024x2048 33,554,432   (Wg^T per expert, k-contig)
//   67108864  Wut  bf16             33,554,432
//   100663296 Wdt  bf16 2048x8192   33,554,432   (Wd^T, k-contig)
//   134217728 H'   bf16 8192x4096   67,108,864   (one expert-halfpass)
//   201326592 Cw   f32  8192x8         262,144   (c[row][e], signed)
//   201588736 part f32  1024             4,096   -> total 201,592,832

typedef short bf16x8 __attribute__((ext_vector_type(8)));
typedef float f32x4 __attribute__((ext_vector_type(4)));
typedef unsigned short u16;

typedef const unsigned int __attribute__((address_space(1)))* as1_u32p;
typedef unsigned int __attribute__((address_space(3)))* as3_u32p;

#define VMCNT6 asm volatile("s_waitcnt vmcnt(6)" ::: "memory")
#define VMCNT0 asm volatile("s_waitcnt vmcnt(0)" ::: "memory")
#define LGKM0  asm volatile("s_waitcnt lgkmcnt(0)" ::: "memory")
#define LGKM4  asm volatile("s_waitcnt lgkmcnt(4)" ::: "memory")
#define LGKM8  asm volatile("s_waitcnt lgkmcnt(8)" ::: "memory")
#define SBAR   __builtin_amdgcn_s_barrier()
#define SCHED0 __builtin_amdgcn_sched_barrier(0)
#define PRIO1  __builtin_amdgcn_s_setprio(1)
#define PRIO0  __builtin_amdgcn_s_setprio(0)
#define MFMA16(af, bf, cf) __builtin_amdgcn_mfma_f32_16x16x32_bf16(af, bf, cf, 0, 0, 0)

__device__ __forceinline__ u16 f2bf(float f) {
  unsigned u = __builtin_bit_cast(unsigned, f);
  u += 0x7fffu + ((u >> 16) & 1u);   // round-to-nearest-even
  return (u16)(u >> 16);
}

__device__ __forceinline__ void gload16(const void* g, const u16* lds) {
  as1_u32p gp = (as1_u32p)(uintptr_t)g;
  as3_u32p lp = (as3_u32p)(unsigned)(uintptr_t)lds;
  __builtin_amdgcn_global_load_lds(gp, lp, 16, 0, 0);
}

// ---------------- router + x->bf16 ----------------
__global__ __launch_bounds__(256) void router_kernel(
    const float* __restrict__ x, const float* __restrict__ Wr,
    float* __restrict__ Cw, u16* __restrict__ Xb) {
  const int l = threadIdx.x & 63;
  const int t = blockIdx.x * 4 + (threadIdx.x >> 6);
  const float* xr = x + (size_t)t * 2048;
  u16* xbr = Xb + (size_t)t * 2048;
  float p[8] = {0.f,0.f,0.f,0.f,0.f,0.f,0.f,0.f};
#pragma unroll
  for (int it = 0; it < 8; ++it) {
    const int d0 = it * 256 + l * 4;
    const float4 xv = *(const float4*)(xr + d0);
    unsigned lo = (unsigned)f2bf(xv.x) | ((unsigned)f2bf(xv.y) << 16);
    unsigned hi = (unsigned)f2bf(xv.z) | ((unsigned)f2bf(xv.w) << 16);
    *(unsigned*)(xbr + d0) = lo;
    *(unsigned*)(xbr + d0 + 2) = hi;
    const float xs[4] = {xv.x, xv.y, xv.z, xv.w};
#pragma unroll
    for (int jj = 0; jj < 4; ++jj) {
      const float4 w0 = *(const float4*)(Wr + (size_t)(d0 + jj) * 8);
      const float4 w1 = *(const float4*)(Wr + (size_t)(d0 + jj) * 8 + 4);
      p[0] += xs[jj] * w0.x; p[1] += xs[jj] * w0.y;
      p[2] += xs[jj] * w0.z; p[3] += xs[jj] * w0.w;
      p[4] += xs[jj] * w1.x; p[5] += xs[jj] * w1.y;
      p[6] += xs[jj] * w1.z; p[7] += xs[jj] * w1.w;
    }
  }
#pragma unroll
  for (int e = 0; e < 8; ++e) {
    float v = p[e];
#pragma unroll
    for (int off = 32; off > 0; off >>= 1) v += __shfl_xor(v, off, 64);
    p[e] = v;
  }
  constexpr float INV_TEMP = 0.36787944117144233f;  // 1/e
  float mx = -1e30f;
#pragma unroll
  for (int e = 0; e < 8; ++e) { p[e] *= INV_TEMP; mx = fmaxf(mx, p[e]); }
  float sum = 0.f;
#pragma unroll
  for (int e = 0; e < 8; ++e) { p[e] = __expf(p[e] - mx); sum += p[e]; }
  const float inv_sum = 1.f / sum;
#pragma unroll
  for (int e = 0; e < 8; ++e) p[e] *= inv_sum;
  // drop the 3 smallest probs (ties: drop higher index, matching top_k)
  unsigned sel = 0xFFu;
  for (int it = 0; it < 3; ++it) {
    float mn = 1e30f; int mi = 0;
#pragma unroll
    for (int e = 0; e < 8; ++e)
      if ((sel >> e) & 1u) { if (p[e] <= mn) { mn = p[e]; mi = e; } }
    sel &= ~(1u << mi);
  }
  float wsum = 0.f;
#pragma unroll
  for (int e = 0; e < 8; ++e) if ((sel >> e) & 1u) wsum += p[e];
  const float inv_w = 1.f / (wsum + 1e-8f);
  if (l == 0) {
#pragma unroll
    for (int e = 0; e < 8; ++e) {
      float v = ((sel >> e) & 1u) ? p[e] * inv_w : 0.f;
      Cw[(size_t)t * 8 + e] = (e < 4) ? v : -v;
    }
  }
}

// ---------------- transpose + fp32->bf16 ----------------
__global__ __launch_bounds__(256) void tcvt_kernel(
    const float* __restrict__ in, u16* __restrict__ out,
    int R, int C, long long ZO, long long CS) {
  __shared__ float tile[32][33];
  const int z = blockIdx.z;
  const float* ib = in + (size_t)z * R * C;
  const int r0 = blockIdx.y * 32, c0 = blockIdx.x * 32;
  const int tx = threadIdx.x, ty = threadIdx.y;  // 32 x 8
#pragma unroll
  for (int j = 0; j < 4; ++j)
    tile[ty + j * 8][tx] = ib[(size_t)(r0 + ty + j * 8) * C + c0 + tx];
  __syncthreads();
#pragma unroll
  for (int j = 0; j < 4; ++j)
    out[(size_t)z * ZO + (size_t)(c0 + ty + j * 8) * CS + r0 + tx] =
        f2bf(tile[tx][ty + j * 8]);
}

// =========== 8-phase 256-wide GEMMs (T1+T2+T3+T4+T5 stack) ===========
// Stage unit = 16KB = 128 rows x 64 k bf16, 2 x global_load_lds(16B)/thread.
// Units/K-tile: {0:Bg/B0, 1:Bu/B1, 2:A0, 3:A1}. Unit j staged >=1 trailing
// barrier after its last reader retires (counted lgkmcnt enforces retire).
// T2 swizzle: LDS granule (row,c) holds global granule c^(row&7); readers
// XOR the same -> 2-way max bank aliasing (free per m136).

// ---------------- GEMM1 (round-4 form: dual G/U, BM=256 BN=128) ----------
__global__ __launch_bounds__(512, 2) void gemm1_8p(
    const u16* __restrict__ Xb, const u16* __restrict__ Wgt,
    const u16* __restrict__ Wut, const float* __restrict__ Cw,
    u16* __restrict__ Hp, int p) {
  extern __shared__ u16 lds[];  // 65536 u16 = 128KB: 2 buf x 4 units x 8192
  const int tid = threadIdx.x;
  const int l = tid & 63, w = tid >> 6;
  const int wr = w >> 2, wc = w & 3;      // 2(M) x 4(N) waves; per-wave 128x32
  const int lq = l >> 4, lr = l & 15;
  const int bid = blockIdx.x;             // 1024 blocks
  const int work = (bid & 7) * 128 + (bid >> 3);   // XCD chunk swizzle
  const int mtile = work & 31;            // 32 M-tiles of 256 rows
  const int en = work >> 5;               // 0..31
  const int el = en >> 3, nt = en & 7;    // expert-local, N-tile
  const int e = p * 4 + el;               // global expert
  const u16* gA  = Xb + (size_t)mtile * 256 * 2048;
  const u16* s0p = Wgt + (size_t)e * 2097152 + (size_t)nt * 128 * 2048;  // Bg
  const u16* s1p = Wut + (size_t)e * 2097152 + (size_t)nt * 128 * 2048;  // Bu
  const u16* s2p = gA;                       // A rows 0-127
  const u16* s3p = gA + (size_t)128 * 2048;  // A rows 128-255
  const int NT = 32;

  auto stageU = [&](int tt, const u16* srcb, int u) {
    if (tt >= NT) return;
    u16* dst = lds + (tt & 1) * 32768 + u * 8192;
    const int kt = tt * 64;
#pragma unroll
    for (int j = 0; j < 2; ++j) {
      const int g = j * 512 + tid;
      const int row = g >> 3;
      const int cg = (g & 7) ^ (row & 7);
      gload16(srcb + (size_t)row * 2048 + kt + cg * 8, dst + g * 8);
    }
  };

  const int xr = lr & 7;
  const int x0 = (lq ^ xr) * 8;
  const int x1 = ((4 + lq) ^ xr) * 8;
  const int aB = (2 + wr) * 8192 + lr * 64;            // + mi*1024 + x
  const int gBo = (wc * 32 + lr) * 64;                 // Bg: + ni*1024 + x
  const int uBo = 8192 + (wc * 32 + lr) * 64;          // Bu

  bf16x8 a[8][2], bg[2][2], bu[2][2];
  f32x4 ag[8][2], au[8][2];
#pragma unroll
  for (int mi = 0; mi < 8; ++mi)
#pragma unroll
    for (int ni = 0; ni < 2; ++ni) {
      ag[mi][ni] = (f32x4){0.f, 0.f, 0.f, 0.f};
      au[mi][ni] = (f32x4){0.f, 0.f, 0.f, 0.f};
    }

  // prologue: tile0 units 0-3, tile1 units 0-2 (7 stages); vmcnt(6) -> t0 in
  stageU(0, s0p, 0); stageU(0, s1p, 1); stageU(0, s2p, 2); stageU(0, s3p, 3);
  stageU(1, s0p, 0); stageU(1, s1p, 1); stageU(1, s2p, 2);
  VMCNT6; SBAR;

  for (int t = 0; t < NT; ++t) {
    const u16* Lb = lds + (t & 1) * 32768;
    // phase 0: read a[0-3], bg; stage A1(t+1); MFMA G m0-3
    {
#pragma unroll
      for (int mi = 0; mi < 4; ++mi) {
        a[mi][0] = *(const bf16x8*)&Lb[aB + mi * 1024 + x0];
        a[mi][1] = *(const bf16x8*)&Lb[aB + mi * 1024 + x1];
      }
#pragma unroll
      for (int ni = 0; ni < 2; ++ni) {
        bg[ni][0] = *(const bf16x8*)&Lb[gBo + ni * 1024 + x0];
        bg[ni][1] = *(const bf16x8*)&Lb[gBo + ni * 1024 + x1];
      }
      stageU(t + 1, s3p, 3);
      SBAR; LGKM0; SCHED0;
      PRIO1;
#pragma unroll
      for (int mi = 0; mi < 4; ++mi)
#pragma unroll
        for (int ni = 0; ni < 2; ++ni)
#pragma unroll
          for (int kk = 0; kk < 2; ++kk)
            ag[mi][ni] = MFMA16(a[mi][kk], bg[ni][kk], ag[mi][ni]);
      PRIO0; SCHED0; SBAR;
    }
    // phase 1: read bu; stage Bg(t+2); MFMA U m0-3
    {
#pragma unroll
      for (int ni = 0; ni < 2; ++ni) {
        bu[ni][0] = *(const bf16x8*)&Lb[uBo + ni * 1024 + x0];
        bu[ni][1] = *(const bf16x8*)&Lb[uBo + ni * 1024 + x1];
      }
      stageU(t + 2, s0p, 0);
      SBAR; LGKM0; SCHED0;
      PRIO1;
#pragma unroll
      for (int mi = 0; mi < 4; ++mi)
#pragma unroll
        for (int ni = 0; ni < 2; ++ni)
#pragma unroll
          for (int kk = 0; kk < 2; ++kk)
            au[mi][ni] = MFMA16(a[mi][kk], bu[ni][kk], au[mi][ni]);
      PRIO0; SCHED0; SBAR;
    }
    // phase 2: read a[4-7]; stage Bu(t+2); MFMA G m4-7
    {
#pragma unroll
      for (int mi = 4; mi < 8; ++mi) {
        a[mi][0] = *(const bf16x8*)&Lb[aB + mi * 1024 + x0];
        a[mi][1] = *(const bf16x8*)&Lb[aB + mi * 1024 + x1];
      }
      stageU(t + 2, s1p, 1);
      SBAR; LGKM0; SCHED0;
      PRIO1;
#pragma unroll
      for (int mi = 4; mi < 8; ++mi)
#pragma unroll
        for (int ni = 0; ni < 2; ++ni)
#pragma unroll
          for (int kk = 0; kk < 2; ++kk)
            ag[mi][ni] = MFMA16(a[mi][kk], bg[ni][kk], ag[mi][ni]);
      PRIO0; SCHED0; SBAR;
    }
    // phase 3: stage A0(t+2); vmcnt; MFMA U m4-7
    {
      stageU(t + 2, s2p, 2);
      if (t < NT - 2) { VMCNT6; } else if (t == NT - 2) { VMCNT0; }
      SBAR; LGKM0; SCHED0;
      PRIO1;
#pragma unroll
      for (int mi = 4; mi < 8; ++mi)
#pragma unroll
        for (int ni = 0; ni < 2; ++ni)
#pragma unroll
          for (int kk = 0; kk < 2; ++kk)
            au[mi][ni] = MFMA16(a[mi][kk], bu[ni][kk], au[mi][ni]);
      PRIO0; SCHED0; SBAR;
    }
  }

  // epilogue: h = silu(g)*u*c -> bf16 into H'[8192 x 4096]
#pragma unroll
  for (int mi = 0; mi < 8; ++mi) {
#pragma unroll
    for (int j = 0; j < 4; ++j) {
      const int row = mtile * 256 + wr * 128 + mi * 16 + lq * 4 + j;
      const float c = Cw[(size_t)row * 8 + e];
#pragma unroll
      for (int ni = 0; ni < 2; ++ni) {
        const float g = ag[mi][ni][j], u = au[mi][ni][j];
        const float h = g * (1.f / (1.f + __expf(-g))) * u * c;
        Hp[(size_t)row * 4096 + el * 1024 + nt * 128 + wc * 32 + ni * 16 + lr] =
            f2bf(h);
      }
    }
  }
}

// -------- GEMM2 (read-ahead pipelined; BM=BN=256, out (+)= H'@Wdt) --------
// Clusters by (m-half, k-half): ph0 = m03*k0, ph1 = m03*k1, ph2 = m47*k0,
// ph3 = m47*k1. Every frag is ds_read >=1 phase before its MFMA cluster:
//   ph3(t-1): bk0(t), bk1(t), a03k0(t)   [12 reads, after vmcnt+SBAR]
//   ph0(t):   a03k1(t)                   [4]
//   ph1(t):   a47k0(t), a47k1(t)         [8]
//   ph2(t):   -
// Counted lgkmcnt before each cluster retires exactly the needed group AND
// enforces readers-retire-before-unit-restage (anti-race):
//   ph0: lgkm(4)  retires ph3-batch (B+a03k0) -> u0/u1 restage safe
//   ph1: lgkm(8)  retires a03k1
//   ph2: lgkm(0)  retires a47k0/k1          -> u2/u3 restage safe
//   ph3: no wait (MFMA operands already retired)
// bk1 ping-pongs across tile parity (bk1A even, bk1B odd) via 2x unroll.
__global__ __launch_bounds__(512, 2) void gemm2_8p(
    const u16* __restrict__ Hp, const u16* __restrict__ Wdt,
    float* __restrict__ out, int koff, int accum) {
  extern __shared__ u16 lds[];
  const int tid = threadIdx.x;
  const int l = tid & 63, w = tid >> 6;
  const int wr = w >> 2, wc = w & 3;      // per-wave 128x64
  const int lq = l >> 4, lr = l & 15;
  const int bid = blockIdx.x;             // 256 blocks
  const int work = (bid & 7) * 32 + (bid >> 3);
  const int mtile = work & 31, ntile = work >> 5;   // 32 x 8
  const u16* gA = Hp + (size_t)mtile * 256 * 4096;             // stride 4096
  const u16* gB = Wdt + (size_t)ntile * 256 * 8192 + koff;     // stride 8192
  const u16* s0p = gB;                       // B rows 0-127
  const u16* s1p = gB + (size_t)128 * 8192;  // B rows 128-255
  const u16* s2p = gA;                       // A rows 0-127
  const u16* s3p = gA + (size_t)128 * 4096;  // A rows 128-255
  const int NT = 64;                         // K = 4096

  const int row0 = tid >> 3,          cg0 = (tid & 7) ^ (row0 & 7);
  const int row1 = (512 + tid) >> 3,  cg1 = ((512 + tid) & 7) ^ (row1 & 7);
  const int offA0 = row0 * 4096 + cg0 * 8, offA1 = row1 * 4096 + cg1 * 8;
  const int offB0 = row0 * 8192 + cg0 * 8, offB1 = row1 * 8192 + cg1 * 8;
  const int d0e = tid * 8, d1e = (512 + tid) * 8;

  auto stageA = [&](int tt, const u16* srcb, int u) {
    if (tt >= NT) return;
    u16* dst = lds + (tt & 1) * 32768 + u * 8192;
    const int kt = tt * 64;
    gload16(srcb + (size_t)(offA0 + kt), dst + d0e);
    gload16(srcb + (size_t)(offA1 + kt), dst + d1e);
  };
  auto stageB = [&](int tt, const u16* srcb, int u) {
    if (tt >= NT) return;
    u16* dst = lds + (tt & 1) * 32768 + u * 8192;
    const int kt = tt * 64;
    gload16(srcb + (size_t)(offB0 + kt), dst + d0e);
    gload16(srcb + (size_t)(offB1 + kt), dst + d1e);
  };

  const int xr = lr & 7;
  const int x0 = (lq ^ xr) * 8;
  const int x1 = ((4 + lq) ^ xr) * 8;
  const int aB = (2 + wr) * 8192 + lr * 64;                    // + mi*1024
  const int bB = (wc >> 1) * 8192 + ((wc & 1) * 64 + lr) * 64; // + ni*1024

  bf16x8 a03k0[4], a03k1[4], a47k0[4], a47k1[4];
  bf16x8 bk0[4], bk1A[4], bk1B[4];
  f32x4 acc[8][4];
#pragma unroll
  for (int mi = 0; mi < 8; ++mi)
#pragma unroll
    for (int ni = 0; ni < 4; ++ni) acc[mi][ni] = (f32x4){0.f, 0.f, 0.f, 0.f};

  stageB(0, s0p, 0); stageB(0, s1p, 1); stageA(0, s2p, 2); stageA(0, s3p, 3);
  stageB(1, s0p, 0); stageB(1, s1p, 1); stageA(1, s2p, 2);
  VMCNT6; SBAR;
  {  // prologue reads for tile 0 (parity 0)
    const u16* Lb = lds;
#pragma unroll
    for (int ni = 0; ni < 4; ++ni) bk0[ni]  = *(const bf16x8*)&Lb[bB + ni * 1024 + x0];
#pragma unroll
    for (int ni = 0; ni < 4; ++ni) bk1A[ni] = *(const bf16x8*)&Lb[bB + ni * 1024 + x1];
#pragma unroll
    for (int mi = 0; mi < 4; ++mi) a03k0[mi] = *(const bf16x8*)&Lb[aB + mi * 1024 + x0];
  }

  for (int i = 0; i < NT / 2; ++i) {
    // ================= even tile t = 2i (parity 0) =================
    {
      const int t = 2 * i;
      const u16* Lb  = lds;
      const u16* Lbn = lds + 32768;
      // ph0: read a03k1; stage A1(t+1); MFMA m03 x k0
#pragma unroll
      for (int mi = 0; mi < 4; ++mi)
        a03k1[mi] = *(const bf16x8*)&Lb[aB + mi * 1024 + x1];
      stageA(t + 1, s3p, 3);
      SBAR; LGKM4; SCHED0;
      PRIO1;
#pragma unroll
      for (int mi = 0; mi < 4; ++mi)
#pragma unroll
        for (int ni = 0; ni < 4; ++ni)
          acc[mi][ni] = MFMA16(a03k0[mi], bk0[ni], acc[mi][ni]);
      PRIO0; SCHED0; SBAR;
      // ph1: read a47k0,a47k1; stage B0(t+2); MFMA m03 x k1
#pragma unroll
      for (int mi = 0; mi < 4; ++mi)
        a47k0[mi] = *(const bf16x8*)&Lb[aB + (4 + mi) * 1024 + x0];
#pragma unroll
      for (int mi = 0; mi < 4; ++mi)
        a47k1[mi] = *(const bf16x8*)&Lb[aB + (4 + mi) * 1024 + x1];
      stageB(t + 2, s0p, 0);
      SBAR; LGKM8; SCHED0;
      PRIO1;
#pragma unroll
      for (int mi = 0; mi < 4; ++mi)
#pragma unroll
        for (int ni = 0; ni < 4; ++ni)
          acc[mi][ni] = MFMA16(a03k1[mi], bk1A[ni], acc[mi][ni]);
      PRIO0; SCHED0; SBAR;
      // ph2: stage B1(t+2); MFMA m47 x k0
      stageB(t + 2, s1p, 1);
      SBAR; LGKM0; SCHED0;
      PRIO1;
#pragma unroll
      for (int mi = 0; mi < 4; ++mi)
#pragma unroll
        for (int ni = 0; ni < 4; ++ni)
          acc[4 + mi][ni] = MFMA16(a47k0[mi], bk0[ni], acc[4 + mi][ni]);
      PRIO0; SCHED0; SBAR;
      // ph3: stage A0(t+2); vmcnt; reads for t+1; MFMA m47 x k1
      stageA(t + 2, s2p, 2);
      if (t < NT - 2) { VMCNT6; } else { VMCNT0; }
      SBAR;
#pragma unroll
      for (int ni = 0; ni < 4; ++ni)
        bk0[ni]  = *(const bf16x8*)&Lbn[bB + ni * 1024 + x0];
#pragma unroll
      for (int ni = 0; ni < 4; ++ni)
        bk1B[ni] = *(const bf16x8*)&Lbn[bB + ni * 1024 + x1];
#pragma unroll
      for (int mi = 0; mi < 4; ++mi)
        a03k0[mi] = *(const bf16x8*)&Lbn[aB + mi * 1024 + x0];
      SCHED0;
      PRIO1;
#pragma unroll
      for (int mi = 0; mi < 4; ++mi)
#pragma unroll
        for (int ni = 0; ni < 4; ++ni)
          acc[4 + mi][ni] = MFMA16(a47k1[mi], bk1A[ni], acc[4 + mi][ni]);
      PRIO0; SCHED0; SBAR;
    }
    // ================= odd tile t = 2i+1 (parity 1) =================
    {
      const int t = 2 * i + 1;
      const u16* Lb  = lds + 32768;
      const u16* Lbn = lds;
      // ph0
#pragma unroll
      for (int mi = 0; mi < 4; ++mi)
        a03k1[mi] = *(const bf16x8*)&Lb[aB + mi * 1024 + x1];
      stageA(t + 1, s3p, 3);
      SBAR; LGKM4; SCHED0;
      PRIO1;
#pragma unroll
      for (int mi = 0; mi < 4; ++mi)
#pragma unroll
        for (int ni = 0; ni < 4; ++ni)
          acc[mi][ni] = MFMA16(a03k0[mi], bk0[ni], acc[mi][ni]);
      PRIO0; SCHED0; SBAR;
      // ph1
#pragma unroll
      for (int mi = 0; mi < 4; ++mi)
        a47k0[mi] = *(const bf16x8*)&Lb[aB + (4 + mi) * 1024 + x0];
#pragma unroll
      for (int mi = 0; mi < 4; ++mi)
        a47k1[mi] = *(const bf16x8*)&Lb[aB + (4 + mi) * 1024 + x1];
      stageB(t + 2, s0p, 0);
      SBAR; LGKM8; SCHED0;
      PRIO1;
#pragma unroll
      for (int mi = 0; mi < 4; ++mi)
#pragma unroll
        for (int ni = 0; ni < 4; ++ni)
          acc[mi][ni] = MFMA16(a03k1[mi], bk1B[ni], acc[mi][ni]);
      PRIO0; SCHED0; SBAR;
      // ph2
      stageB(t + 2, s1p, 1);
      SBAR; LGKM0; SCHED0;
      PRIO1;
#pragma unroll
      for (int mi = 0; mi < 4; ++mi)
#pragma unroll
        for (int ni = 0; ni < 4; ++ni)
          acc[4 + mi][ni] = MFMA16(a47k0[mi], bk0[ni], acc[4 + mi][ni]);
      PRIO0; SCHED0; SBAR;
      // ph3
      stageA(t + 2, s2p, 2);
      if (t < NT - 2) { VMCNT6; }
      SBAR;
      if (i < NT / 2 - 1) {
#pragma unroll
        for (int ni = 0; ni < 4; ++ni)
          bk0[ni]  = *(const bf16x8*)&Lbn[bB + ni * 1024 + x0];
#pragma unroll
        for (int ni = 0; ni < 4; ++ni)
          bk1A[ni] = *(const bf16x8*)&Lbn[bB + ni * 1024 + x1];
#pragma unroll
        for (int mi = 0; mi < 4; ++mi)
          a03k0[mi] = *(const bf16x8*)&Lbn[aB + mi * 1024 + x0];
      }
      SCHED0;
      PRIO1;
#pragma unroll
      for (int mi = 0; mi < 4; ++mi)
#pragma unroll
        for (int ni = 0; ni < 4; ++ni)
          acc[4 + mi][ni] = MFMA16(a47k1[mi], bk1B[ni], acc[4 + mi][ni]);
      PRIO0; SCHED0; SBAR;
    }
  }

#pragma unroll
  for (int mi = 0; mi < 8; ++mi)
#pragma unroll
    for (int ni = 0; ni < 4; ++ni)
#pragma unroll
      for (int j = 0; j < 4; ++j) {
        const int row = mtile * 256 + wr * 128 + mi * 16 + lq * 4 + j;
        const int col = ntile * 256 + wc * 64 + ni * 16 + lr;
        const size_t idx = (size_t)row * 2048 + col;
        float v = acc[mi][ni][j];
        if (accum) v += out[idx];
        out[idx] = v;
      }
}

// ---------------- tension scalar: mean(output^2) ----------------
__global__ __launch_bounds__(256) void sqsum_partial(
    const float* __restrict__ out, float* __restrict__ part, int n4) {
  float s = 0.f;
  const int idx = blockIdx.x * 256 + threadIdx.x;
  const int stride = gridDim.x * 256;
  for (int i = idx; i < n4; i += stride) {
    const float4 v = ((const float4*)out)[i];
    s += v.x * v.x + v.y * v.y + v.z * v.z + v.w * v.w;
  }
#pragma unroll
  for (int off = 32; off > 0; off >>= 1) s += __shfl_down(s, off, 64);
  __shared__ float ls[4];
  if ((threadIdx.x & 63) == 0) ls[threadIdx.x >> 6] = s;
  __syncthreads();
  if (threadIdx.x == 0) part[blockIdx.x] = ls[0] + ls[1] + ls[2] + ls[3];
}

__global__ __launch_bounds__(256) void sqsum_final(
    const float* __restrict__ part, float* __restrict__ dst, int np, float scale) {
  float s = 0.f;
  for (int i = threadIdx.x; i < np; i += 256) s += part[i];
#pragma unroll
  for (int off = 32; off > 0; off >>= 1) s += __shfl_down(s, off, 64);
  __shared__ float ls[4];
  if ((threadIdx.x & 63) == 0) ls[threadIdx.x >> 6] = s;
  __syncthreads();
  if (threadIdx.x == 0) dst[0] = (ls[0] + ls[1] + ls[2] + ls[3]) * scale;
}

// ---------------- launch ----------------
extern "C" void kernel_launch(void* const* d_in, const int* in_sizes, int n_in,
                              void* d_out, int out_size, void* d_ws, size_t ws_size,
                              hipStream_t stream) {
  (void)in_sizes; (void)n_in; (void)out_size; (void)ws_size;
  const float* x  = (const float*)d_in[0];
  const float* Wr = (const float*)d_in[1];
  const float* Wg = (const float*)d_in[2];
  const float* Wu = (const float*)d_in[3];
  const float* Wd = (const float*)d_in[4];
  float* out = (float*)d_out;
  char* ws = (char*)d_ws;
  u16*   Xb   = (u16*)(ws);
  u16*   Wgt  = (u16*)(ws + 33554432);
  u16*   Wut  = (u16*)(ws + 67108864);
  u16*   Wdt  = (u16*)(ws + 100663296);
  u16*   Hp   = (u16*)(ws + 134217728);
  float* Cw   = (float*)(ws + 201326592);
  float* part = (float*)(ws + 201588736);

  (void)hipFuncSetAttribute((const void*)gemm1_8p,
                            hipFuncAttributeMaxDynamicSharedMemorySize, 131072);
  (void)hipFuncSetAttribute((const void*)gemm2_8p,
                            hipFuncAttributeMaxDynamicSharedMemorySize, 131072);

  router_kernel<<<2048, 256, 0, stream>>>(x, Wr, Cw, Xb);

  dim3 tb(32, 8);
  tcvt_kernel<<<dim3(32, 64, 8), tb, 0, stream>>>(Wg, Wgt, 2048, 1024, 2097152LL, 2048LL);
  tcvt_kernel<<<dim3(32, 64, 8), tb, 0, stream>>>(Wu, Wut, 2048, 1024, 2097152LL, 2048LL);
  tcvt_kernel<<<dim3(64, 32, 8), tb, 0, stream>>>(Wd, Wdt, 1024, 2048, 1024LL, 8192LL);

  for (int p = 0; p < 2; ++p) {
    gemm1_8p<<<1024, 512, 131072, stream>>>(Xb, Wgt, Wut, Cw, Hp, p);
    gemm2_8p<<<256, 512, 131072, stream>>>(Hp, Wdt, out, p * 4096, p);
  }

  sqsum_partial<<<1024, 256, 0, stream>>>(out, part, 16777216 / 4);
  sqsum_final<<<1, 256, 0, stream>>>(part, out + 16777216, 1024, 1.f / 16777216.f);
}

// Round 7
// 821.969 us; speedup vs baseline: 1.1628x; 1.1628x over previous
//
#include <hip/hip_runtime.h>
#include <cstdint>
#include <cstddef>

// AnimaMLP: router(top-5 of 8, softmax/e) + 8 dense experts (silu(xWg)*xWu)Wd,
// signed-weighted sum, plus mean(output^2) scalar.
//
// Expert-chunked 8-phase plan + top-5 token gather (exact: dropped experts
// have weight exactly 0; their H' rows are memset zeros = dense result).
//   pass p in {0,1}: experts 4p..4p+3
//     memset H' = 0
//     gemm1_8p (1024 blocks, ~64% active): H'[idx[t], :] for selected tokens
//     gemm2_8p (round-4 form): out (+)= H' @ Wdt[:, 4096p..]
// ws map (bytes):
//   0         Xb   bf16 8192x2048   33,554,432
//   33554432  Wgt  bf16 8x1024x2048 33,554,432   (Wg^T per expert, k-contig)
//   67108864  Wut  bf16             33,554,432
//   100663296 Wdt  bf16 2048x8192   33,554,432   (Wd^T, k-contig)
//   134217728 H'   bf16 8192x4096   67,108,864   (one expert-halfpass)
//   201326592 Cw   f32  8192x8         262,144   (c[row][e], signed)
//   201588736 part f32  1024             4,096
//   201592832 idx  i32  8x8192         262,144   (sparse path only)
//   201854976 cnt  i32  8                   32   -> total 201,855,008

typedef short bf16x8 __attribute__((ext_vector_type(8)));
typedef float f32x4 __attribute__((ext_vector_type(4)));
typedef unsigned short u16;

typedef const unsigned int __attribute__((address_space(1)))* as1_u32p;
typedef unsigned int __attribute__((address_space(3)))* as3_u32p;

#define VMCNT6 asm volatile("s_waitcnt vmcnt(6)" ::: "memory")
#define VMCNT0 asm volatile("s_waitcnt vmcnt(0)" ::: "memory")
#define LGKM0  asm volatile("s_waitcnt lgkmcnt(0)" ::: "memory")
#define SBAR   __builtin_amdgcn_s_barrier()
#define SCHED0 __builtin_amdgcn_sched_barrier(0)
#define PRIO1  __builtin_amdgcn_s_setprio(1)
#define PRIO0  __builtin_amdgcn_s_setprio(0)
#define MFMA16(af, bf, cf) __builtin_amdgcn_mfma_f32_16x16x32_bf16(af, bf, cf, 0, 0, 0)

__device__ __forceinline__ u16 f2bf(float f) {
  unsigned u = __builtin_bit_cast(unsigned, f);
  u += 0x7fffu + ((u >> 16) & 1u);   // round-to-nearest-even
  return (u16)(u >> 16);
}

__device__ __forceinline__ void gload16(const void* g, const u16* lds) {
  as1_u32p gp = (as1_u32p)(uintptr_t)g;
  as3_u32p lp = (as3_u32p)(unsigned)(uintptr_t)lds;
  __builtin_amdgcn_global_load_lds(gp, lp, 16, 0, 0);
}

// ---------------- router + x->bf16 ----------------
__global__ __launch_bounds__(256) void router_kernel(
    const float* __restrict__ x, const float* __restrict__ Wr,
    float* __restrict__ Cw, u16* __restrict__ Xb) {
  const int l = threadIdx.x & 63;
  const int t = blockIdx.x * 4 + (threadIdx.x >> 6);
  const float* xr = x + (size_t)t * 2048;
  u16* xbr = Xb + (size_t)t * 2048;
  float p[8] = {0.f,0.f,0.f,0.f,0.f,0.f,0.f,0.f};
#pragma unroll
  for (int it = 0; it < 8; ++it) {
    const int d0 = it * 256 + l * 4;
    const float4 xv = *(const float4*)(xr + d0);
    unsigned lo = (unsigned)f2bf(xv.x) | ((unsigned)f2bf(xv.y) << 16);
    unsigned hi = (unsigned)f2bf(xv.z) | ((unsigned)f2bf(xv.w) << 16);
    *(unsigned*)(xbr + d0) = lo;
    *(unsigned*)(xbr + d0 + 2) = hi;
    const float xs[4] = {xv.x, xv.y, xv.z, xv.w};
#pragma unroll
    for (int jj = 0; jj < 4; ++jj) {
      const float4 w0 = *(const float4*)(Wr + (size_t)(d0 + jj) * 8);
      const float4 w1 = *(const float4*)(Wr + (size_t)(d0 + jj) * 8 + 4);
      p[0] += xs[jj] * w0.x; p[1] += xs[jj] * w0.y;
      p[2] += xs[jj] * w0.z; p[3] += xs[jj] * w0.w;
      p[4] += xs[jj] * w1.x; p[5] += xs[jj] * w1.y;
      p[6] += xs[jj] * w1.z; p[7] += xs[jj] * w1.w;
    }
  }
#pragma unroll
  for (int e = 0; e < 8; ++e) {
    float v = p[e];
#pragma unroll
    for (int off = 32; off > 0; off >>= 1) v += __shfl_xor(v, off, 64);
    p[e] = v;
  }
  constexpr float INV_TEMP = 0.36787944117144233f;  // 1/e
  float mx = -1e30f;
#pragma unroll
  for (int e = 0; e < 8; ++e) { p[e] *= INV_TEMP; mx = fmaxf(mx, p[e]); }
  float sum = 0.f;
#pragma unroll
  for (int e = 0; e < 8; ++e) { p[e] = __expf(p[e] - mx); sum += p[e]; }
  const float inv_sum = 1.f / sum;
#pragma unroll
  for (int e = 0; e < 8; ++e) p[e] *= inv_sum;
  // drop the 3 smallest probs (ties: drop higher index, matching top_k)
  unsigned sel = 0xFFu;
  for (int it = 0; it < 3; ++it) {
    float mn = 1e30f; int mi = 0;
#pragma unroll
    for (int e = 0; e < 8; ++e)
      if ((sel >> e) & 1u) { if (p[e] <= mn) { mn = p[e]; mi = e; } }
    sel &= ~(1u << mi);
  }
  float wsum = 0.f;
#pragma unroll
  for (int e = 0; e < 8; ++e) if ((sel >> e) & 1u) wsum += p[e];
  const float inv_w = 1.f / (wsum + 1e-8f);
  if (l == 0) {
#pragma unroll
    for (int e = 0; e < 8; ++e) {
      float v = ((sel >> e) & 1u) ? p[e] * inv_w : 0.f;
      Cw[(size_t)t * 8 + e] = (e < 4) ? v : -v;
    }
  }
}

// ------------- per-expert token compaction (sorted, deterministic) -------
__global__ __launch_bounds__(256) void build_idx(
    const float* __restrict__ Cw, int* __restrict__ idx, int* __restrict__ cnt) {
  const int e = blockIdx.x;           // 8 blocks
  const int tid = threadIdx.x;        // each thread scans 32 tokens
  const int t0 = tid * 32;
  int c = 0;
#pragma unroll
  for (int j = 0; j < 32; ++j)
    if (Cw[(size_t)(t0 + j) * 8 + e] != 0.f) ++c;
  __shared__ int s[256];
  s[tid] = c;
  __syncthreads();
  for (int off = 1; off < 256; off <<= 1) {
    int v = (tid >= off) ? s[tid - off] : 0;
    __syncthreads();
    s[tid] += v;
    __syncthreads();
  }
  int o = e * 8192 + s[tid] - c;      // exclusive prefix
  for (int j = 0; j < 32; ++j) {
    const int t = t0 + j;
    if (Cw[(size_t)t * 8 + e] != 0.f) idx[o++] = t;
  }
  if (tid == 255) cnt[e] = s[255];
}

// ---------------- transpose + fp32->bf16 ----------------
__global__ __launch_bounds__(256) void tcvt_kernel(
    const float* __restrict__ in, u16* __restrict__ out,
    int R, int C, long long ZO, long long CS) {
  __shared__ float tile[32][33];
  const int z = blockIdx.z;
  const float* ib = in + (size_t)z * R * C;
  const int r0 = blockIdx.y * 32, c0 = blockIdx.x * 32;
  const int tx = threadIdx.x, ty = threadIdx.y;  // 32 x 8
#pragma unroll
  for (int j = 0; j < 4; ++j)
    tile[ty + j * 8][tx] = ib[(size_t)(r0 + ty + j * 8) * C + c0 + tx];
  __syncthreads();
#pragma unroll
  for (int j = 0; j < 4; ++j)
    out[(size_t)z * ZO + (size_t)(c0 + ty + j * 8) * CS + r0 + tx] =
        f2bf(tile[tx][ty + j * 8]);
}

// =========== 8-phase 256-wide GEMMs (T1+T2+T3+T4+T5 stack) ===========
// Stage unit = 16KB = 128 rows x 64 k bf16, 2 x global_load_lds(16B)/thread.
// Units/K-tile: {0:Bg/B0, 1:Bu/B1, 2:A0, 3:A1}; each staged >=1 trailing
// barrier after its last reader. T2 swizzle: LDS granule (row,c) holds global
// granule c^(row&7); readers XOR the same -> 2-way max aliasing (free).

// -------- GEMM1 (dual G/U, BM=256 BN=128, optional token-gather) --------
__global__ __launch_bounds__(512, 2) void gemm1_8p(
    const u16* __restrict__ Xb, const u16* __restrict__ Wgt,
    const u16* __restrict__ Wut, const float* __restrict__ Cw,
    u16* __restrict__ Hp, const int* __restrict__ idx,
    const int* __restrict__ cnt, int p) {
  extern __shared__ u16 lds[];  // 65536 u16 = 128KB: 2 buf x 4 units x 8192
  const int tid = threadIdx.x;
  const int l = tid & 63, w = tid >> 6;
  const int wr = w >> 2, wc = w & 3;      // 2(M) x 4(N) waves; per-wave 128x32
  const int lq = l >> 4, lr = l & 15;
  const int bid = blockIdx.x;             // 1024 blocks
  const int work = (bid & 7) * 128 + (bid >> 3);   // XCD chunk swizzle
  const int mtile = work & 31;
  const int en = work >> 5;
  const int el = en >> 3, nt = en & 7;
  const int e = p * 4 + el;
  const int cnt_e = idx ? cnt[e] : 8192;
  const int base = mtile * 256;
  if (base >= cnt_e) return;              // empty tile: exit before barriers
  const int* idxp = idx ? idx + (size_t)e * 8192 : nullptr;

  const u16* s0p = Wgt + (size_t)e * 2097152 + (size_t)nt * 128 * 2048;  // Bg
  const u16* s1p = Wut + (size_t)e * 2097152 + (size_t)nt * 128 * 2048;  // Bu

  const int lrow = tid >> 3;
  const int cgo = ((tid & 7) ^ (lrow & 7)) * 8;
  const int offB0 = lrow * 2048 + cgo;
  const int offB1 = offB0 + 64 * 2048;
  const int d0e = tid * 8, d1e = (512 + tid) * 8;

  auto gr = [&](int r) -> size_t {        // gathered A-row base (elements)
    const int rr = r < cnt_e ? r : cnt_e - 1;
    return (size_t)(idxp ? idxp[rr] : rr) * 2048 + cgo;
  };
  const size_t a20 = gr(base + lrow);
  const size_t a21 = gr(base + 64 + lrow);
  const size_t a30 = gr(base + 128 + lrow);
  const size_t a31 = gr(base + 192 + lrow);

  const int NT = 32;
  auto stageB = [&](int tt, const u16* srcb, int u) {
    if (tt >= NT) return;
    u16* dst = lds + (tt & 1) * 32768 + u * 8192;
    const int kt = tt * 64;
    gload16(srcb + offB0 + kt, dst + d0e);
    gload16(srcb + offB1 + kt, dst + d1e);
  };
  auto stageA = [&](int tt, size_t b0, size_t b1, int u) {
    if (tt >= NT) return;
    u16* dst = lds + (tt & 1) * 32768 + u * 8192;
    const int kt = tt * 64;
    gload16(Xb + b0 + kt, dst + d0e);
    gload16(Xb + b1 + kt, dst + d1e);
  };

  const int xr = lr & 7;
  const int x0 = (lq ^ xr) * 8;
  const int x1 = ((4 + lq) ^ xr) * 8;
  const int aB = (2 + wr) * 8192 + lr * 64;            // + mi*1024 + x
  const int gBo = (wc * 32 + lr) * 64;                 // Bg: + ni*1024 + x
  const int uBo = 8192 + (wc * 32 + lr) * 64;          // Bu

  bf16x8 a[8][2], bg[2][2], bu[2][2];
  f32x4 ag[8][2], au[8][2];
#pragma unroll
  for (int mi = 0; mi < 8; ++mi)
#pragma unroll
    for (int ni = 0; ni < 2; ++ni) {
      ag[mi][ni] = (f32x4){0.f, 0.f, 0.f, 0.f};
      au[mi][ni] = (f32x4){0.f, 0.f, 0.f, 0.f};
    }

  // prologue: tile0 units 0-3, tile1 units 0-2 (7 stages); vmcnt(6) -> t0 in
  stageB(0, s0p, 0); stageB(0, s1p, 1);
  stageA(0, a20, a21, 2); stageA(0, a30, a31, 3);
  stageB(1, s0p, 0); stageB(1, s1p, 1); stageA(1, a20, a21, 2);
  VMCNT6; SBAR;

  for (int t = 0; t < NT; ++t) {
    const u16* Lb = lds + (t & 1) * 32768;
    // phase 0: read a[0-3], bg; stage A1(t+1); MFMA G m0-3
    {
#pragma unroll
      for (int mi = 0; mi < 4; ++mi) {
        a[mi][0] = *(const bf16x8*)&Lb[aB + mi * 1024 + x0];
        a[mi][1] = *(const bf16x8*)&Lb[aB + mi * 1024 + x1];
      }
#pragma unroll
      for (int ni = 0; ni < 2; ++ni) {
        bg[ni][0] = *(const bf16x8*)&Lb[gBo + ni * 1024 + x0];
        bg[ni][1] = *(const bf16x8*)&Lb[gBo + ni * 1024 + x1];
      }
      stageA(t + 1, a30, a31, 3);
      SBAR; LGKM0; SCHED0;
      PRIO1;
#pragma unroll
      for (int mi = 0; mi < 4; ++mi)
#pragma unroll
        for (int ni = 0; ni < 2; ++ni)
#pragma unroll
          for (int kk = 0; kk < 2; ++kk)
            ag[mi][ni] = MFMA16(a[mi][kk], bg[ni][kk], ag[mi][ni]);
      PRIO0; SCHED0; SBAR;
    }
    // phase 1: read bu; stage Bg(t+2); MFMA U m0-3
    {
#pragma unroll
      for (int ni = 0; ni < 2; ++ni) {
        bu[ni][0] = *(const bf16x8*)&Lb[uBo + ni * 1024 + x0];
        bu[ni][1] = *(const bf16x8*)&Lb[uBo + ni * 1024 + x1];
      }
      stageB(t + 2, s0p, 0);
      SBAR; LGKM0; SCHED0;
      PRIO1;
#pragma unroll
      for (int mi = 0; mi < 4; ++mi)
#pragma unroll
        for (int ni = 0; ni < 2; ++ni)
#pragma unroll
          for (int kk = 0; kk < 2; ++kk)
            au[mi][ni] = MFMA16(a[mi][kk], bu[ni][kk], au[mi][ni]);
      PRIO0; SCHED0; SBAR;
    }
    // phase 2: read a[4-7]; stage Bu(t+2); MFMA G m4-7
    {
#pragma unroll
      for (int mi = 4; mi < 8; ++mi) {
        a[mi][0] = *(const bf16x8*)&Lb[aB + mi * 1024 + x0];
        a[mi][1] = *(const bf16x8*)&Lb[aB + mi * 1024 + x1];
      }
      stageB(t + 2, s1p, 1);
      SBAR; LGKM0; SCHED0;
      PRIO1;
#pragma unroll
      for (int mi = 4; mi < 8; ++mi)
#pragma unroll
        for (int ni = 0; ni < 2; ++ni)
#pragma unroll
          for (int kk = 0; kk < 2; ++kk)
            ag[mi][ni] = MFMA16(a[mi][kk], bg[ni][kk], ag[mi][ni]);
      PRIO0; SCHED0; SBAR;
    }
    // phase 3: stage A0(t+2); vmcnt; MFMA U m4-7
    {
      stageA(t + 2, a20, a21, 2);
      if (t < NT - 2) { VMCNT6; } else if (t == NT - 2) { VMCNT0; }
      SBAR; LGKM0; SCHED0;
      PRIO1;
#pragma unroll
      for (int mi = 4; mi < 8; ++mi)
#pragma unroll
        for (int ni = 0; ni < 2; ++ni)
#pragma unroll
          for (int kk = 0; kk < 2; ++kk)
            au[mi][ni] = MFMA16(a[mi][kk], bu[ni][kk], au[mi][ni]);
      PRIO0; SCHED0; SBAR;
    }
  }

  // epilogue: h = silu(g)*u*c -> bf16 into H'[orig_row, 4096]
#pragma unroll
  for (int mi = 0; mi < 8; ++mi) {
#pragma unroll
    for (int j = 0; j < 4; ++j) {
      const int rl = wr * 128 + mi * 16 + lq * 4 + j;
      const int grow = base + rl;
      if (grow < cnt_e) {
        const int orow = idxp ? idxp[grow] : grow;
        const float c = Cw[(size_t)orow * 8 + e];
#pragma unroll
        for (int ni = 0; ni < 2; ++ni) {
          const float g = ag[mi][ni][j], u = au[mi][ni][j];
          const float h = g * (1.f / (1.f + __expf(-g))) * u * c;
          Hp[(size_t)orow * 4096 + el * 1024 + nt * 128 + wc * 32 + ni * 16 + lr] =
              f2bf(h);
        }
      }
    }
  }
}

// ---------------- GEMM2 (round-4 form; BM=BN=256, out (+)= H'@Wdt) --------
__global__ __launch_bounds__(512, 2) void gemm2_8p(
    const u16* __restrict__ Hp, const u16* __restrict__ Wdt,
    float* __restrict__ out, int koff, int accum) {
  extern __shared__ u16 lds[];
  const int tid = threadIdx.x;
  const int l = tid & 63, w = tid >> 6;
  const int wr = w >> 2, wc = w & 3;      // per-wave 128x64
  const int lq = l >> 4, lr = l & 15;
  const int bid = blockIdx.x;             // 256 blocks
  const int work = (bid & 7) * 32 + (bid >> 3);
  const int mtile = work & 31, ntile = work >> 5;   // 32 x 8
  const u16* gA = Hp + (size_t)mtile * 256 * 4096;             // stride 4096
  const u16* gB = Wdt + (size_t)ntile * 256 * 8192 + koff;     // stride 8192
  const u16* s0p = gB;                       // B rows 0-127
  const u16* s1p = gB + (size_t)128 * 8192;  // B rows 128-255
  const u16* s2p = gA;                       // A rows 0-127
  const u16* s3p = gA + (size_t)128 * 4096;  // A rows 128-255
  const int NT = 64;                         // K = 4096

  const int row0 = tid >> 3,          cg0 = (tid & 7) ^ (row0 & 7);
  const int row1 = (512 + tid) >> 3,  cg1 = ((512 + tid) & 7) ^ (row1 & 7);
  const int offA0 = row0 * 4096 + cg0 * 8, offA1 = row1 * 4096 + cg1 * 8;
  const int offB0 = row0 * 8192 + cg0 * 8, offB1 = row1 * 8192 + cg1 * 8;
  const int d0e = tid * 8, d1e = (512 + tid) * 8;

  auto stageA = [&](int tt, const u16* srcb, int u) {
    if (tt >= NT) return;
    u16* dst = lds + (tt & 1) * 32768 + u * 8192;
    const int kt = tt * 64;
    gload16(srcb + (size_t)(offA0 + kt), dst + d0e);
    gload16(srcb + (size_t)(offA1 + kt), dst + d1e);
  };
  auto stageB = [&](int tt, const u16* srcb, int u) {
    if (tt >= NT) return;
    u16* dst = lds + (tt & 1) * 32768 + u * 8192;
    const int kt = tt * 64;
    gload16(srcb + (size_t)(offB0 + kt), dst + d0e);
    gload16(srcb + (size_t)(offB1 + kt), dst + d1e);
  };

  const int xr = lr & 7;
  const int x0 = (lq ^ xr) * 8;
  const int x1 = ((4 + lq) ^ xr) * 8;
  const int aB = (2 + wr) * 8192 + lr * 64;                    // + mi*1024
  const int bB = (wc >> 1) * 8192 + ((wc & 1) * 64 + lr) * 64; // + ni*1024

  bf16x8 a[8][2], b[4][2];
  f32x4 acc[8][4];
#pragma unroll
  for (int mi = 0; mi < 8; ++mi)
#pragma unroll
    for (int ni = 0; ni < 4; ++ni) acc[mi][ni] = (f32x4){0.f, 0.f, 0.f, 0.f};

  stageB(0, s0p, 0); stageB(0, s1p, 1); stageA(0, s2p, 2); stageA(0, s3p, 3);
  stageB(1, s0p, 0); stageB(1, s1p, 1); stageA(1, s2p, 2);
  VMCNT6; SBAR;

  for (int t = 0; t < NT; ++t) {
    const u16* Lb = lds + (t & 1) * 32768;
    // phase 0: read a[0-3], b[0-1] (+wc<2: b[2-3]); stage A1(t+1); MFMA m0-3 n0-1
    {
#pragma unroll
      for (int mi = 0; mi < 4; ++mi) {
        a[mi][0] = *(const bf16x8*)&Lb[aB + mi * 1024 + x0];
        a[mi][1] = *(const bf16x8*)&Lb[aB + mi * 1024 + x1];
      }
#pragma unroll
      for (int ni = 0; ni < 2; ++ni) {
        b[ni][0] = *(const bf16x8*)&Lb[bB + ni * 1024 + x0];
        b[ni][1] = *(const bf16x8*)&Lb[bB + ni * 1024 + x1];
      }
      if (wc < 2) {
#pragma unroll
        for (int ni = 2; ni < 4; ++ni) {
          b[ni][0] = *(const bf16x8*)&Lb[bB + ni * 1024 + x0];
          b[ni][1] = *(const bf16x8*)&Lb[bB + ni * 1024 + x1];
        }
      }
      stageA(t + 1, s3p, 3);
      SBAR; LGKM0; SCHED0;
      PRIO1;
#pragma unroll
      for (int mi = 0; mi < 4; ++mi)
#pragma unroll
        for (int ni = 0; ni < 2; ++ni)
#pragma unroll
          for (int kk = 0; kk < 2; ++kk)
            acc[mi][ni] = MFMA16(a[mi][kk], b[ni][kk], acc[mi][ni]);
      PRIO0; SCHED0; SBAR;
    }
    // phase 1: wc>=2 read b[2-3]; stage B0(t+2); MFMA m0-3 n2-3
    {
      if (wc >= 2) {
#pragma unroll
        for (int ni = 2; ni < 4; ++ni) {
          b[ni][0] = *(const bf16x8*)&Lb[bB + ni * 1024 + x0];
          b[ni][1] = *(const bf16x8*)&Lb[bB + ni * 1024 + x1];
        }
      }
      stageB(t + 2, s0p, 0);
      SBAR; LGKM0; SCHED0;
      PRIO1;
#pragma unroll
      for (int mi = 0; mi < 4; ++mi)
#pragma unroll
        for (int ni = 2; ni < 4; ++ni)
#pragma unroll
          for (int kk = 0; kk < 2; ++kk)
            acc[mi][ni] = MFMA16(a[mi][kk], b[ni][kk], acc[mi][ni]);
      PRIO0; SCHED0; SBAR;
    }
    // phase 2: read a[4-7]; stage B1(t+2); MFMA m4-7 n2-3
    {
#pragma unroll
      for (int mi = 4; mi < 8; ++mi) {
        a[mi][0] = *(const bf16x8*)&Lb[aB + mi * 1024 + x0];
        a[mi][1] = *(const bf16x8*)&Lb[aB + mi * 1024 + x1];
      }
      stageB(t + 2, s1p, 1);
      SBAR; LGKM0; SCHED0;
      PRIO1;
#pragma unroll
      for (int mi = 4; mi < 8; ++mi)
#pragma unroll
        for (int ni = 2; ni < 4; ++ni)
#pragma unroll
          for (int kk = 0; kk < 2; ++kk)
            acc[mi][ni] = MFMA16(a[mi][kk], b[ni][kk], acc[mi][ni]);
      PRIO0; SCHED0; SBAR;
    }
    // phase 3: stage A0(t+2); vmcnt; MFMA m4-7 n0-1
    {
      stageA(t + 2, s2p, 2);
      if (t < NT - 2) { VMCNT6; } else if (t == NT - 2) { VMCNT0; }
      SBAR; LGKM0; SCHED0;
      PRIO1;
#pragma unroll
      for (int mi = 4; mi < 8; ++mi)
#pragma unroll
        for (int ni = 0; ni < 2; ++ni)
#pragma unroll
          for (int kk = 0; kk < 2; ++kk)
            acc[mi][ni] = MFMA16(a[mi][kk], b[ni][kk], acc[mi][ni]);
      PRIO0; SCHED0; SBAR;
    }
  }

#pragma unroll
  for (int mi = 0; mi < 8; ++mi)
#pragma unroll
    for (int ni = 0; ni < 4; ++ni)
#pragma unroll
      for (int j = 0; j < 4; ++j) {
        const int row = mtile * 256 + wr * 128 + mi * 16 + lq * 4 + j;
        const int col = ntile * 256 + wc * 64 + ni * 16 + lr;
        const size_t idx2 = (size_t)row * 2048 + col;
        float v = acc[mi][ni][j];
        if (accum) v += out[idx2];
        out[idx2] = v;
      }
}

// ---------------- tension scalar: mean(output^2) ----------------
__global__ __launch_bounds__(256) void sqsum_partial(
    const float* __restrict__ out, float* __restrict__ part, int n4) {
  float s = 0.f;
  const int idx = blockIdx.x * 256 + threadIdx.x;
  const int stride = gridDim.x * 256;
  for (int i = idx; i < n4; i += stride) {
    const float4 v = ((const float4*)out)[i];
    s += v.x * v.x + v.y * v.y + v.z * v.z + v.w * v.w;
  }
#pragma unroll
  for (int off = 32; off > 0; off >>= 1) s += __shfl_down(s, off, 64);
  __shared__ float ls[4];
  if ((threadIdx.x & 63) == 0) ls[threadIdx.x >> 6] = s;
  __syncthreads();
  if (threadIdx.x == 0) part[blockIdx.x] = ls[0] + ls[1] + ls[2] + ls[3];
}

__global__ __launch_bounds__(256) void sqsum_final(
    const float* __restrict__ part, float* __restrict__ dst, int np, float scale) {
  float s = 0.f;
  for (int i = threadIdx.x; i < np; i += 256) s += part[i];
#pragma unroll
  for (int off = 32; off > 0; off >>= 1) s += __shfl_down(s, off, 64);
  __shared__ float ls[4];
  if ((threadIdx.x & 63) == 0) ls[threadIdx.x >> 6] = s;
  __syncthreads();
  if (threadIdx.x == 0) dst[0] = (ls[0] + ls[1] + ls[2] + ls[3]) * scale;
}

// ---------------- launch ----------------
extern "C" void kernel_launch(void* const* d_in, const int* in_sizes, int n_in,
                              void* d_out, int out_size, void* d_ws, size_t ws_size,
                              hipStream_t stream) {
  (void)in_sizes; (void)n_in; (void)out_size;
  const float* x  = (const float*)d_in[0];
  const float* Wr = (const float*)d_in[1];
  const float* Wg = (const float*)d_in[2];
  const float* Wu = (const float*)d_in[3];
  const float* Wd = (const float*)d_in[4];
  float* out = (float*)d_out;
  char* ws = (char*)d_ws;
  u16*   Xb   = (u16*)(ws);
  u16*   Wgt  = (u16*)(ws + 33554432);
  u16*   Wut  = (u16*)(ws + 67108864);
  u16*   Wdt  = (u16*)(ws + 100663296);
  u16*   Hp   = (u16*)(ws + 134217728);
  float* Cw   = (float*)(ws + 201326592);
  float* part = (float*)(ws + 201588736);
  const bool SPARSE = ws_size >= 201855008u;
  int* idxbuf = SPARSE ? (int*)(ws + 201592832) : nullptr;
  int* cntbuf = SPARSE ? (int*)(ws + 201854976) : nullptr;

  (void)hipFuncSetAttribute((const void*)gemm1_8p,
                            hipFuncAttributeMaxDynamicSharedMemorySize, 131072);
  (void)hipFuncSetAttribute((const void*)gemm2_8p,
                            hipFuncAttributeMaxDynamicSharedMemorySize, 131072);

  router_kernel<<<2048, 256, 0, stream>>>(x, Wr, Cw, Xb);
  if (SPARSE) build_idx<<<8, 256, 0, stream>>>(Cw, idxbuf, cntbuf);

  dim3 tb(32, 8);
  tcvt_kernel<<<dim3(32, 64, 8), tb, 0, stream>>>(Wg, Wgt, 2048, 1024, 2097152LL, 2048LL);
  tcvt_kernel<<<dim3(32, 64, 8), tb, 0, stream>>>(Wu, Wut, 2048, 1024, 2097152LL, 2048LL);
  tcvt_kernel<<<dim3(64, 32, 8), tb, 0, stream>>>(Wd, Wdt, 1024, 2048, 1024LL, 8192LL);

  for (int p = 0; p < 2; ++p) {
    if (SPARSE) (void)hipMemsetAsync(Hp, 0, 67108864, stream);
    gemm1_8p<<<1024, 512, 131072, stream>>>(Xb, Wgt, Wut, Cw, Hp,
                                            idxbuf, cntbuf, p);
    gemm2_8p<<<256, 512, 131072, stream>>>(Hp, Wdt, out, p * 4096, p);
  }

  sqsum_partial<<<1024, 256, 0, stream>>>(out, part, 16777216 / 4);
  sqsum_final<<<1, 256, 0, stream>>>(part, out + 16777216, 1024, 1.f / 16777216.f);
}

// Round 8
// 806.431 us; speedup vs baseline: 1.1852x; 1.0193x over previous
//
#include <hip/hip_runtime.h>
#include <cstdint>
#include <cstddef>

// AnimaMLP: router(top-5 of 8, softmax/e) + 8 dense experts (silu(xWg)*xWu)Wd,
// signed-weighted sum, plus mean(output^2) scalar.
//
// Expert-chunked 8-phase plan + top-5 token gather (exact: dropped experts
// have weight exactly 0; their H' rows are zero-filled = dense result).
//   pass p in {0,1}: experts 4p..4p+3
//     zerofill inactive (t,el) ranges of H'
//     gemm1_8p (1024 blocks, ~64% active): H'[idx[t], :] for selected tokens
//     gemm2_8p: out (+)= H' @ Wdt[:, 4096p..]; accum pass also emits sq-sums
// ws map (bytes):
//   0         Xb   bf16 8192x2048   33,554,432
//   33554432  Wgt  bf16 8x1024x2048 33,554,432   (Wg^T per expert, k-contig)
//   67108864  Wut  bf16             33,554,432
//   100663296 Wdt  bf16 2048x8192   33,554,432   (Wd^T, k-contig)
//   134217728 H'   bf16 8192x4096   67,108,864   (one expert-halfpass)
//   201326592 Cw   f32  8192x8         262,144   (c[row][e], signed)
//   201588736 part f32  1024             4,096
//   201592832 idx  i32  8x8192         262,144   (sparse path only)
//   201854976 cnt  i32  8                   32   -> total 201,855,008

typedef short bf16x8 __attribute__((ext_vector_type(8)));
typedef float f32x4 __attribute__((ext_vector_type(4)));
typedef unsigned short u16;

typedef const unsigned int __attribute__((address_space(1)))* as1_u32p;
typedef unsigned int __attribute__((address_space(3)))* as3_u32p;

#define VMCNT6 asm volatile("s_waitcnt vmcnt(6)" ::: "memory")
#define VMCNT0 asm volatile("s_waitcnt vmcnt(0)" ::: "memory")
#define LGKM0  asm volatile("s_waitcnt lgkmcnt(0)" ::: "memory")
#define LGKM8  asm volatile("s_waitcnt lgkmcnt(8)" ::: "memory")
#define SBAR   __builtin_amdgcn_s_barrier()
#define SCHED0 __builtin_amdgcn_sched_barrier(0)
#define PRIO1  __builtin_amdgcn_s_setprio(1)
#define PRIO0  __builtin_amdgcn_s_setprio(0)
#define MFMA16(af, bf, cf) __builtin_amdgcn_mfma_f32_16x16x32_bf16(af, bf, cf, 0, 0, 0)

__device__ __forceinline__ u16 f2bf(float f) {
  unsigned u = __builtin_bit_cast(unsigned, f);
  u += 0x7fffu + ((u >> 16) & 1u);   // round-to-nearest-even
  return (u16)(u >> 16);
}

__device__ __forceinline__ void gload16(const void* g, const u16* lds) {
  as1_u32p gp = (as1_u32p)(uintptr_t)g;
  as3_u32p lp = (as3_u32p)(unsigned)(uintptr_t)lds;
  __builtin_amdgcn_global_load_lds(gp, lp, 16, 0, 0);
}

// ---------------- router + x->bf16 ----------------
__global__ __launch_bounds__(256) void router_kernel(
    const float* __restrict__ x, const float* __restrict__ Wr,
    float* __restrict__ Cw, u16* __restrict__ Xb) {
  const int l = threadIdx.x & 63;
  const int t = blockIdx.x * 4 + (threadIdx.x >> 6);
  const float* xr = x + (size_t)t * 2048;
  u16* xbr = Xb + (size_t)t * 2048;
  float p[8] = {0.f,0.f,0.f,0.f,0.f,0.f,0.f,0.f};
#pragma unroll
  for (int it = 0; it < 8; ++it) {
    const int d0 = it * 256 + l * 4;
    const float4 xv = *(const float4*)(xr + d0);
    unsigned lo = (unsigned)f2bf(xv.x) | ((unsigned)f2bf(xv.y) << 16);
    unsigned hi = (unsigned)f2bf(xv.z) | ((unsigned)f2bf(xv.w) << 16);
    *(unsigned*)(xbr + d0) = lo;
    *(unsigned*)(xbr + d0 + 2) = hi;
    const float xs[4] = {xv.x, xv.y, xv.z, xv.w};
#pragma unroll
    for (int jj = 0; jj < 4; ++jj) {
      const float4 w0 = *(const float4*)(Wr + (size_t)(d0 + jj) * 8);
      const float4 w1 = *(const float4*)(Wr + (size_t)(d0 + jj) * 8 + 4);
      p[0] += xs[jj] * w0.x; p[1] += xs[jj] * w0.y;
      p[2] += xs[jj] * w0.z; p[3] += xs[jj] * w0.w;
      p[4] += xs[jj] * w1.x; p[5] += xs[jj] * w1.y;
      p[6] += xs[jj] * w1.z; p[7] += xs[jj] * w1.w;
    }
  }
#pragma unroll
  for (int e = 0; e < 8; ++e) {
    float v = p[e];
#pragma unroll
    for (int off = 32; off > 0; off >>= 1) v += __shfl_xor(v, off, 64);
    p[e] = v;
  }
  constexpr float INV_TEMP = 0.36787944117144233f;  // 1/e
  float mx = -1e30f;
#pragma unroll
  for (int e = 0; e < 8; ++e) { p[e] *= INV_TEMP; mx = fmaxf(mx, p[e]); }
  float sum = 0.f;
#pragma unroll
  for (int e = 0; e < 8; ++e) { p[e] = __expf(p[e] - mx); sum += p[e]; }
  const float inv_sum = 1.f / sum;
#pragma unroll
  for (int e = 0; e < 8; ++e) p[e] *= inv_sum;
  // drop the 3 smallest probs (ties: drop higher index, matching top_k)
  unsigned sel = 0xFFu;
  for (int it = 0; it < 3; ++it) {
    float mn = 1e30f; int mi = 0;
#pragma unroll
    for (int e = 0; e < 8; ++e)
      if ((sel >> e) & 1u) { if (p[e] <= mn) { mn = p[e]; mi = e; } }
    sel &= ~(1u << mi);
  }
  float wsum = 0.f;
#pragma unroll
  for (int e = 0; e < 8; ++e) if ((sel >> e) & 1u) wsum += p[e];
  const float inv_w = 1.f / (wsum + 1e-8f);
  if (l == 0) {
#pragma unroll
    for (int e = 0; e < 8; ++e) {
      float v = ((sel >> e) & 1u) ? p[e] * inv_w : 0.f;
      Cw[(size_t)t * 8 + e] = (e < 4) ? v : -v;
    }
  }
}

// ------------- per-expert token compaction (sorted, deterministic) -------
__global__ __launch_bounds__(256) void build_idx(
    const float* __restrict__ Cw, int* __restrict__ idx, int* __restrict__ cnt) {
  const int e = blockIdx.x;           // 8 blocks
  const int tid = threadIdx.x;        // each thread scans 32 tokens
  const int t0 = tid * 32;
  int c = 0;
#pragma unroll
  for (int j = 0; j < 32; ++j)
    if (Cw[(size_t)(t0 + j) * 8 + e] != 0.f) ++c;
  __shared__ int s[256];
  s[tid] = c;
  __syncthreads();
  for (int off = 1; off < 256; off <<= 1) {
    int v = (tid >= off) ? s[tid - off] : 0;
    __syncthreads();
    s[tid] += v;
    __syncthreads();
  }
  int o = e * 8192 + s[tid] - c;      // exclusive prefix
  for (int j = 0; j < 32; ++j) {
    const int t = t0 + j;
    if (Cw[(size_t)t * 8 + e] != 0.f) idx[o++] = t;
  }
  if (tid == 255) cnt[e] = s[255];
}

// ------------- zero-fill inactive (token, expert) H' ranges -------------
__global__ __launch_bounds__(256) void zerofill(
    const float* __restrict__ Cw, u16* __restrict__ Hp, int p) {
  const int t = blockIdx.x * 4 + (threadIdx.x >> 6);   // 2048 blocks
  const int l = threadIdx.x & 63;
  bf16x8* rowp = (bf16x8*)(Hp + (size_t)t * 4096);
  const bf16x8 z = {0, 0, 0, 0, 0, 0, 0, 0};
#pragma unroll
  for (int el = 0; el < 4; ++el) {
    if (Cw[(size_t)t * 8 + p * 4 + el] == 0.f) {
      rowp[el * 128 + l] = z;
      rowp[el * 128 + 64 + l] = z;
    }
  }
}

// ---------------- transpose + fp32->bf16 (64x64 tiles) ----------------
// out[z*ZO + c*CS + r] = bf16(in[z*R*C + r*C + c]); blockDim (64,4)
__global__ __launch_bounds__(256) void tcvt_kernel(
    const float* __restrict__ in, u16* __restrict__ out,
    int R, int C, long long ZO, long long CS) {
  __shared__ float tile[64][65];
  const int z = blockIdx.z;
  const float* ib = in + (size_t)z * R * C;
  const int r0 = blockIdx.y * 64, c0 = blockIdx.x * 64;
  const int tx = threadIdx.x, ty = threadIdx.y;  // 64 x 4
#pragma unroll
  for (int j = 0; j < 16; ++j)
    tile[ty + j * 4][tx] = ib[(size_t)(r0 + ty + j * 4) * C + c0 + tx];
  __syncthreads();
#pragma unroll
  for (int j = 0; j < 16; ++j)
    out[(size_t)z * ZO + (size_t)(c0 + ty + j * 4) * CS + r0 + tx] =
        f2bf(tile[tx][ty + j * 4]);
}

// =========== 8-phase 256-wide GEMMs (T1+T2+T3+T4+T5 stack) ===========
// Stage unit = 16KB = 128 rows x 64 k bf16, 2 x global_load_lds(16B)/thread.
// Units/K-tile: {0:Bg/B0, 1:Bu/B1, 2:A0, 3:A1}; each staged >=1 trailing
// barrier after its last reader. T2 swizzle: LDS granule (row,c) holds global
// granule c^(row&7); readers XOR the same -> 2-way max aliasing (free).

// -------- GEMM1 (dual G/U, BM=256 BN=128, optional token-gather) --------
__global__ __launch_bounds__(512, 2) void gemm1_8p(
    const u16* __restrict__ Xb, const u16* __restrict__ Wgt,
    const u16* __restrict__ Wut, const float* __restrict__ Cw,
    u16* __restrict__ Hp, const int* __restrict__ idx,
    const int* __restrict__ cnt, int p) {
  extern __shared__ u16 lds[];  // 65536 u16 = 128KB: 2 buf x 4 units x 8192
  const int tid = threadIdx.x;
  const int l = tid & 63, w = tid >> 6;
  const int wr = w >> 2, wc = w & 3;      // 2(M) x 4(N) waves; per-wave 128x32
  const int lq = l >> 4, lr = l & 15;
  const int bid = blockIdx.x;             // 1024 blocks
  const int work = (bid & 7) * 128 + (bid >> 3);   // XCD chunk swizzle
  const int mtile = work & 31;
  const int en = work >> 5;
  const int el = en >> 3, nt = en & 7;
  const int e = p * 4 + el;
  const int cnt_e = idx ? cnt[e] : 8192;
  const int base = mtile * 256;
  if (base >= cnt_e) return;              // empty tile: exit before barriers
  const int* idxp = idx ? idx + (size_t)e * 8192 : nullptr;

  const u16* s0p = Wgt + (size_t)e * 2097152 + (size_t)nt * 128 * 2048;  // Bg
  const u16* s1p = Wut + (size_t)e * 2097152 + (size_t)nt * 128 * 2048;  // Bu

  const int lrow = tid >> 3;
  const int cgo = ((tid & 7) ^ (lrow & 7)) * 8;
  const int offB0 = lrow * 2048 + cgo;
  const int offB1 = offB0 + 64 * 2048;
  const int d0e = tid * 8, d1e = (512 + tid) * 8;

  auto gr = [&](int r) -> size_t {        // gathered A-row base (elements)
    const int rr = r < cnt_e ? r : cnt_e - 1;
    return (size_t)(idxp ? idxp[rr] : rr) * 2048 + cgo;
  };
  const size_t a20 = gr(base + lrow);
  const size_t a21 = gr(base + 64 + lrow);
  const size_t a30 = gr(base + 128 + lrow);
  const size_t a31 = gr(base + 192 + lrow);

  const int NT = 32;
  auto stageB = [&](int tt, const u16* srcb, int u) {
    if (tt >= NT) return;
    u16* dst = lds + (tt & 1) * 32768 + u * 8192;
    const int kt = tt * 64;
    gload16(srcb + offB0 + kt, dst + d0e);
    gload16(srcb + offB1 + kt, dst + d1e);
  };
  auto stageA = [&](int tt, size_t b0, size_t b1, int u) {
    if (tt >= NT) return;
    u16* dst = lds + (tt & 1) * 32768 + u * 8192;
    const int kt = tt * 64;
    gload16(Xb + b0 + kt, dst + d0e);
    gload16(Xb + b1 + kt, dst + d1e);
  };

  const int xr = lr & 7;
  const int x0 = (lq ^ xr) * 8;
  const int x1 = ((4 + lq) ^ xr) * 8;
  const int aB = (2 + wr) * 8192 + lr * 64;            // + mi*1024 + x
  const int gBo = (wc * 32 + lr) * 64;                 // Bg: + ni*1024 + x
  const int uBo = 8192 + (wc * 32 + lr) * 64;          // Bu

  bf16x8 a[8][2], bg[2][2], bu[2][2];
  f32x4 ag[8][2], au[8][2];
#pragma unroll
  for (int mi = 0; mi < 8; ++mi)
#pragma unroll
    for (int ni = 0; ni < 2; ++ni) {
      ag[mi][ni] = (f32x4){0.f, 0.f, 0.f, 0.f};
      au[mi][ni] = (f32x4){0.f, 0.f, 0.f, 0.f};
    }

  // prologue: tile0 units 0-3, tile1 units 0-2 (7 stages); vmcnt(6) -> t0 in
  stageB(0, s0p, 0); stageB(0, s1p, 1);
  stageA(0, a20, a21, 2); stageA(0, a30, a31, 3);
  stageB(1, s0p, 0); stageB(1, s1p, 1); stageA(1, a20, a21, 2);
  VMCNT6; SBAR;

  for (int t = 0; t < NT; ++t) {
    const u16* Lb = lds + (t & 1) * 32768;
    // phase 0: read a[0-3], bg (12); stage A1(t+1); MFMA G m0-3
    {
#pragma unroll
      for (int mi = 0; mi < 4; ++mi) {
        a[mi][0] = *(const bf16x8*)&Lb[aB + mi * 1024 + x0];
        a[mi][1] = *(const bf16x8*)&Lb[aB + mi * 1024 + x1];
      }
#pragma unroll
      for (int ni = 0; ni < 2; ++ni) {
        bg[ni][0] = *(const bf16x8*)&Lb[gBo + ni * 1024 + x0];
        bg[ni][1] = *(const bf16x8*)&Lb[gBo + ni * 1024 + x1];
      }
      stageA(t + 1, a30, a31, 3);
      LGKM8; SBAR; LGKM0; SCHED0;
      PRIO1;
#pragma unroll
      for (int mi = 0; mi < 4; ++mi)
#pragma unroll
        for (int ni = 0; ni < 2; ++ni)
#pragma unroll
          for (int kk = 0; kk < 2; ++kk)
            ag[mi][ni] = MFMA16(a[mi][kk], bg[ni][kk], ag[mi][ni]);
      PRIO0; SCHED0; SBAR;
    }
    // phase 1: read bu; stage Bg(t+2); MFMA U m0-3
    {
#pragma unroll
      for (int ni = 0; ni < 2; ++ni) {
        bu[ni][0] = *(const bf16x8*)&Lb[uBo + ni * 1024 + x0];
        bu[ni][1] = *(const bf16x8*)&Lb[uBo + ni * 1024 + x1];
      }
      stageB(t + 2, s0p, 0);
      SBAR; LGKM0; SCHED0;
      PRIO1;
#pragma unroll
      for (int mi = 0; mi < 4; ++mi)
#pragma unroll
        for (int ni = 0; ni < 2; ++ni)
#pragma unroll
          for (int kk = 0; kk < 2; ++kk)
            au[mi][ni] = MFMA16(a[mi][kk], bu[ni][kk], au[mi][ni]);
      PRIO0; SCHED0; SBAR;
    }
    // phase 2: read a[4-7]; stage Bu(t+2); MFMA G m4-7
    {
#pragma unroll
      for (int mi = 4; mi < 8; ++mi) {
        a[mi][0] = *(const bf16x8*)&Lb[aB + mi * 1024 + x0];
        a[mi][1] = *(const bf16x8*)&Lb[aB + mi * 1024 + x1];
      }
      stageB(t + 2, s1p, 1);
      SBAR; LGKM0; SCHED0;
      PRIO1;
#pragma unroll
      for (int mi = 4; mi < 8; ++mi)
#pragma unroll
        for (int ni = 0; ni < 2; ++ni)
#pragma unroll
          for (int kk = 0; kk < 2; ++kk)
            ag[mi][ni] = MFMA16(a[mi][kk], bg[ni][kk], ag[mi][ni]);
      PRIO0; SCHED0; SBAR;
    }
    // phase 3: stage A0(t+2); vmcnt; MFMA U m4-7
    {
      stageA(t + 2, a20, a21, 2);
      if (t < NT - 2) { VMCNT6; } else if (t == NT - 2) { VMCNT0; }
      SBAR; LGKM0; SCHED0;
      PRIO1;
#pragma unroll
      for (int mi = 4; mi < 8; ++mi)
#pragma unroll
        for (int ni = 0; ni < 2; ++ni)
#pragma unroll
          for (int kk = 0; kk < 2; ++kk)
            au[mi][ni] = MFMA16(a[mi][kk], bu[ni][kk], au[mi][ni]);
      PRIO0; SCHED0; SBAR;
    }
  }

  // epilogue: h = silu(g)*u*c -> bf16 into H'[orig_row, 4096]
#pragma unroll
  for (int mi = 0; mi < 8; ++mi) {
#pragma unroll
    for (int j = 0; j < 4; ++j) {
      const int rl = wr * 128 + mi * 16 + lq * 4 + j;
      const int grow = base + rl;
      if (grow < cnt_e) {
        const int orow = idxp ? idxp[grow] : grow;
        const float c = Cw[(size_t)orow * 8 + e];
#pragma unroll
        for (int ni = 0; ni < 2; ++ni) {
          const float g = ag[mi][ni][j], u = au[mi][ni][j];
          const float h = g * (1.f / (1.f + __expf(-g))) * u * c;
          Hp[(size_t)orow * 4096 + el * 1024 + nt * 128 + wc * 32 + ni * 16 + lr] =
              f2bf(h);
        }
      }
    }
  }
}

// ---------------- GEMM2 (BM=BN=256, out (+)= H'@Wdt; accum emits sqsum) --
__global__ __launch_bounds__(512, 2) void gemm2_8p(
    const u16* __restrict__ Hp, const u16* __restrict__ Wdt,
    float* __restrict__ out, float* __restrict__ part, int koff, int accum) {
  extern __shared__ u16 lds[];
  const int tid = threadIdx.x;
  const int l = tid & 63, w = tid >> 6;
  const int wr = w >> 2, wc = w & 3;      // per-wave 128x64
  const int lq = l >> 4, lr = l & 15;
  const int bid = blockIdx.x;             // 256 blocks
  const int work = (bid & 7) * 32 + (bid >> 3);
  const int mtile = work & 31, ntile = work >> 5;   // 32 x 8
  const u16* gA = Hp + (size_t)mtile * 256 * 4096;             // stride 4096
  const u16* gB = Wdt + (size_t)ntile * 256 * 8192 + koff;     // stride 8192
  const u16* s0p = gB;                       // B rows 0-127
  const u16* s1p = gB + (size_t)128 * 8192;  // B rows 128-255
  const u16* s2p = gA;                       // A rows 0-127
  const u16* s3p = gA + (size_t)128 * 4096;  // A rows 128-255
  const int NT = 64;                         // K = 4096

  const int row0 = tid >> 3,          cg0 = (tid & 7) ^ (row0 & 7);
  const int row1 = (512 + tid) >> 3,  cg1 = ((512 + tid) & 7) ^ (row1 & 7);
  const int offA0 = row0 * 4096 + cg0 * 8, offA1 = row1 * 4096 + cg1 * 8;
  const int offB0 = row0 * 8192 + cg0 * 8, offB1 = row1 * 8192 + cg1 * 8;
  const int d0e = tid * 8, d1e = (512 + tid) * 8;

  auto stageA = [&](int tt, const u16* srcb, int u) {
    if (tt >= NT) return;
    u16* dst = lds + (tt & 1) * 32768 + u * 8192;
    const int kt = tt * 64;
    gload16(srcb + (size_t)(offA0 + kt), dst + d0e);
    gload16(srcb + (size_t)(offA1 + kt), dst + d1e);
  };
  auto stageB = [&](int tt, const u16* srcb, int u) {
    if (tt >= NT) return;
    u16* dst = lds + (tt & 1) * 32768 + u * 8192;
    const int kt = tt * 64;
    gload16(srcb + (size_t)(offB0 + kt), dst + d0e);
    gload16(srcb + (size_t)(offB1 + kt), dst + d1e);
  };

  const int xr = lr & 7;
  const int x0 = (lq ^ xr) * 8;
  const int x1 = ((4 + lq) ^ xr) * 8;
  const int aB = (2 + wr) * 8192 + lr * 64;                    // + mi*1024
  const int bB = (wc >> 1) * 8192 + ((wc & 1) * 64 + lr) * 64; // + ni*1024

  bf16x8 a[8][2], b[4][2];
  f32x4 acc[8][4];
#pragma unroll
  for (int mi = 0; mi < 8; ++mi)
#pragma unroll
    for (int ni = 0; ni < 4; ++ni) acc[mi][ni] = (f32x4){0.f, 0.f, 0.f, 0.f};

  stageB(0, s0p, 0); stageB(0, s1p, 1); stageA(0, s2p, 2); stageA(0, s3p, 3);
  stageB(1, s0p, 0); stageB(1, s1p, 1); stageA(1, s2p, 2);
  VMCNT6; SBAR;

  for (int t = 0; t < NT; ++t) {
    const u16* Lb = lds + (t & 1) * 32768;
    // phase 0: read a[0-3], b[0-1] (+wc<2: b[2-3]); stage A1(t+1); MFMA m0-3 n0-1
    {
#pragma unroll
      for (int mi = 0; mi < 4; ++mi) {
        a[mi][0] = *(const bf16x8*)&Lb[aB + mi * 1024 + x0];
        a[mi][1] = *(const bf16x8*)&Lb[aB + mi * 1024 + x1];
      }
#pragma unroll
      for (int ni = 0; ni < 2; ++ni) {
        b[ni][0] = *(const bf16x8*)&Lb[bB + ni * 1024 + x0];
        b[ni][1] = *(const bf16x8*)&Lb[bB + ni * 1024 + x1];
      }
      if (wc < 2) {
#pragma unroll
        for (int ni = 2; ni < 4; ++ni) {
          b[ni][0] = *(const bf16x8*)&Lb[bB + ni * 1024 + x0];
          b[ni][1] = *(const bf16x8*)&Lb[bB + ni * 1024 + x1];
        }
      }
      stageA(t + 1, s3p, 3);
      LGKM8; SBAR; LGKM0; SCHED0;
      PRIO1;
#pragma unroll
      for (int mi = 0; mi < 4; ++mi)
#pragma unroll
        for (int ni = 0; ni < 2; ++ni)
#pragma unroll
          for (int kk = 0; kk < 2; ++kk)
            acc[mi][ni] = MFMA16(a[mi][kk], b[ni][kk], acc[mi][ni]);
      PRIO0; SCHED0; SBAR;
    }
    // phase 1: wc>=2 read b[2-3]; stage B0(t+2); MFMA m0-3 n2-3
    {
      if (wc >= 2) {
#pragma unroll
        for (int ni = 2; ni < 4; ++ni) {
          b[ni][0] = *(const bf16x8*)&Lb[bB + ni * 1024 + x0];
          b[ni][1] = *(const bf16x8*)&Lb[bB + ni * 1024 + x1];
        }
      }
      stageB(t + 2, s0p, 0);
      SBAR; LGKM0; SCHED0;
      PRIO1;
#pragma unroll
      for (int mi = 0; mi < 4; ++mi)
#pragma unroll
        for (int ni = 2; ni < 4; ++ni)
#pragma unroll
          for (int kk = 0; kk < 2; ++kk)
            acc[mi][ni] = MFMA16(a[mi][kk], b[ni][kk], acc[mi][ni]);
      PRIO0; SCHED0; SBAR;
    }
    // phase 2: read a[4-7]; stage B1(t+2); MFMA m4-7 n2-3
    {
#pragma unroll
      for (int mi = 4; mi < 8; ++mi) {
        a[mi][0] = *(const bf16x8*)&Lb[aB + mi * 1024 + x0];
        a[mi][1] = *(const bf16x8*)&Lb[aB + mi * 1024 + x1];
      }
      stageB(t + 2, s1p, 1);
      SBAR; LGKM0; SCHED0;
      PRIO1;
#pragma unroll
      for (int mi = 4; mi < 8; ++mi)
#pragma unroll
        for (int ni = 2; ni < 4; ++ni)
#pragma unroll
          for (int kk = 0; kk < 2; ++kk)
            acc[mi][ni] = MFMA16(a[mi][kk], b[ni][kk], acc[mi][ni]);
      PRIO0; SCHED0; SBAR;
    }
    // phase 3: stage A0(t+2); vmcnt; MFMA m4-7 n0-1
    {
      stageA(t + 2, s2p, 2);
      if (t < NT - 2) { VMCNT6; } else if (t == NT - 2) { VMCNT0; }
      SBAR; LGKM0; SCHED0;
      PRIO1;
#pragma unroll
      for (int mi = 4; mi < 8; ++mi)
#pragma unroll
        for (int ni = 0; ni < 2; ++ni)
#pragma unroll
          for (int kk = 0; kk < 2; ++kk)
            acc[mi][ni] = MFMA16(a[mi][kk], b[ni][kk], acc[mi][ni]);
      PRIO0; SCHED0; SBAR;
    }
  }

  float sq = 0.f;
#pragma unroll
  for (int mi = 0; mi < 8; ++mi)
#pragma unroll
    for (int ni = 0; ni < 4; ++ni)
#pragma unroll
      for (int j = 0; j < 4; ++j) {
        const int row = mtile * 256 + wr * 128 + mi * 16 + lq * 4 + j;
        const int col = ntile * 256 + wc * 64 + ni * 16 + lr;
        const size_t idx2 = (size_t)row * 2048 + col;
        float v = acc[mi][ni][j];
        if (accum) { v += out[idx2]; sq += v * v; }
        out[idx2] = v;
      }
  if (accum) {
#pragma unroll
    for (int off = 32; off > 0; off >>= 1) sq += __shfl_down(sq, off, 64);
    __syncthreads();                       // K-loop LDS no longer needed
    float* sm = (float*)lds;
    if (l == 0) sm[w] = sq;
    __syncthreads();
    if (tid == 0) {
      float tot = 0.f;
#pragma unroll
      for (int i = 0; i < 8; ++i) tot += sm[i];
      part[bid] = tot;
    }
  }
}

// ---------------- tension scalar final reduce ----------------
__global__ __launch_bounds__(256) void sqsum_final(
    const float* __restrict__ part, float* __restrict__ dst, int np, float scale) {
  float s = 0.f;
  for (int i = threadIdx.x; i < np; i += 256) s += part[i];
#pragma unroll
  for (int off = 32; off > 0; off >>= 1) s += __shfl_down(s, off, 64);
  __shared__ float ls[4];
  if ((threadIdx.x & 63) == 0) ls[threadIdx.x >> 6] = s;
  __syncthreads();
  if (threadIdx.x == 0) dst[0] = (ls[0] + ls[1] + ls[2] + ls[3]) * scale;
}

// ---------------- launch ----------------
extern "C" void kernel_launch(void* const* d_in, const int* in_sizes, int n_in,
                              void* d_out, int out_size, void* d_ws, size_t ws_size,
                              hipStream_t stream) {
  (void)in_sizes; (void)n_in; (void)out_size;
  const float* x  = (const float*)d_in[0];
  const float* Wr = (const float*)d_in[1];
  const float* Wg = (const float*)d_in[2];
  const float* Wu = (const float*)d_in[3];
  const float* Wd = (const float*)d_in[4];
  float* out = (float*)d_out;
  char* ws = (char*)d_ws;
  u16*   Xb   = (u16*)(ws);
  u16*   Wgt  = (u16*)(ws + 33554432);
  u16*   Wut  = (u16*)(ws + 67108864);
  u16*   Wdt  = (u16*)(ws + 100663296);
  u16*   Hp   = (u16*)(ws + 134217728);
  float* Cw   = (float*)(ws + 201326592);
  float* part = (float*)(ws + 201588736);
  const bool SPARSE = ws_size >= 201855008u;
  int* idxbuf = SPARSE ? (int*)(ws + 201592832) : nullptr;
  int* cntbuf = SPARSE ? (int*)(ws + 201854976) : nullptr;

  (void)hipFuncSetAttribute((const void*)gemm1_8p,
                            hipFuncAttributeMaxDynamicSharedMemorySize, 131072);
  (void)hipFuncSetAttribute((const void*)gemm2_8p,
                            hipFuncAttributeMaxDynamicSharedMemorySize, 131072);

  router_kernel<<<2048, 256, 0, stream>>>(x, Wr, Cw, Xb);
  if (SPARSE) build_idx<<<8, 256, 0, stream>>>(Cw, idxbuf, cntbuf);

  dim3 tb(64, 4);
  tcvt_kernel<<<dim3(16, 32, 8), tb, 0, stream>>>(Wg, Wgt, 2048, 1024, 2097152LL, 2048LL);
  tcvt_kernel<<<dim3(16, 32, 8), tb, 0, stream>>>(Wu, Wut, 2048, 1024, 2097152LL, 2048LL);
  tcvt_kernel<<<dim3(32, 16, 8), tb, 0, stream>>>(Wd, Wdt, 1024, 2048, 1024LL, 8192LL);

  for (int p = 0; p < 2; ++p) {
    if (SPARSE) zerofill<<<2048, 256, 0, stream>>>(Cw, Hp, p);
    gemm1_8p<<<1024, 512, 131072, stream>>>(Xb, Wgt, Wut, Cw, Hp,
                                            idxbuf, cntbuf, p);
    gemm2_8p<<<256, 512, 131072, stream>>>(Hp, Wdt, out, part, p * 4096, p);
  }

  sqsum_final<<<1, 256, 0, stream>>>(part, out + 16777216, 256, 1.f / 16777216.f);
}

// Round 9
// 805.223 us; speedup vs baseline: 1.1870x; 1.0015x over previous
//
#include <hip/hip_runtime.h>
#include <cstdint>
#include <cstddef>

// AnimaMLP: router(top-5 of 8, softmax/e) + 8 dense experts (silu(xWg)*xWu)Wd,
// signed-weighted sum, plus mean(output^2) scalar.
//
// Expert-chunked 8-phase plan + top-5 token gather (exact: dropped experts
// have weight exactly 0; their H' rows are zero-filled = dense result).
//   pass p in {0,1}: experts 4p..4p+3
//     zerofill inactive (t,el) ranges of H'
//     gemm1_8p (1024 blocks, ~64% active): H'[idx[t], :] for selected tokens
//     gemm2_8p: out (+)= H' @ Wdt[:, 4096p..]; accum pass also emits sq-sums
// Phase read balance (8,4,8,4): next-tile B-frags read at ph3 after the
// vmcnt+barrier (arrival guaranteed) and after ph3's MFMA (B dead there).
// ws map (bytes):
//   0         Xb   bf16 8192x2048   33,554,432
//   33554432  Wgt  bf16 8x1024x2048 33,554,432   (Wg^T per expert, k-contig)
//   67108864  Wut  bf16             33,554,432
//   100663296 Wdt  bf16 2048x8192   33,554,432   (Wd^T, k-contig)
//   134217728 H'   bf16 8192x4096   67,108,864   (one expert-halfpass)
//   201326592 Cw   f32  8192x8         262,144   (c[row][e], signed)
//   201588736 part f32  1024             4,096
//   201592832 idx  i32  8x8192         262,144   (sparse path only)
//   201854976 cnt  i32  8                   32   -> total 201,855,008

typedef short bf16x8 __attribute__((ext_vector_type(8)));
typedef float f32x4 __attribute__((ext_vector_type(4)));
typedef unsigned short u16;

typedef const unsigned int __attribute__((address_space(1)))* as1_u32p;
typedef unsigned int __attribute__((address_space(3)))* as3_u32p;

#define VMCNT6 asm volatile("s_waitcnt vmcnt(6)" ::: "memory")
#define VMCNT0 asm volatile("s_waitcnt vmcnt(0)" ::: "memory")
#define LGKM0  asm volatile("s_waitcnt lgkmcnt(0)" ::: "memory")
#define LGKM4  asm volatile("s_waitcnt lgkmcnt(4)" ::: "memory")
#define SBAR   __builtin_amdgcn_s_barrier()
#define SCHED0 __builtin_amdgcn_sched_barrier(0)
#define PRIO1  __builtin_amdgcn_s_setprio(1)
#define PRIO0  __builtin_amdgcn_s_setprio(0)
#define MFMA16(af, bf, cf) __builtin_amdgcn_mfma_f32_16x16x32_bf16(af, bf, cf, 0, 0, 0)

__device__ __forceinline__ u16 f2bf(float f) {
  unsigned u = __builtin_bit_cast(unsigned, f);
  u += 0x7fffu + ((u >> 16) & 1u);   // round-to-nearest-even
  return (u16)(u >> 16);
}

__device__ __forceinline__ void gload16(const void* g, const u16* lds) {
  as1_u32p gp = (as1_u32p)(uintptr_t)g;
  as3_u32p lp = (as3_u32p)(unsigned)(uintptr_t)lds;
  __builtin_amdgcn_global_load_lds(gp, lp, 16, 0, 0);
}

// ---------------- router + x->bf16 ----------------
__global__ __launch_bounds__(256) void router_kernel(
    const float* __restrict__ x, const float* __restrict__ Wr,
    float* __restrict__ Cw, u16* __restrict__ Xb) {
  const int l = threadIdx.x & 63;
  const int t = blockIdx.x * 4 + (threadIdx.x >> 6);
  const float* xr = x + (size_t)t * 2048;
  u16* xbr = Xb + (size_t)t * 2048;
  float p[8] = {0.f,0.f,0.f,0.f,0.f,0.f,0.f,0.f};
#pragma unroll
  for (int it = 0; it < 8; ++it) {
    const int d0 = it * 256 + l * 4;
    const float4 xv = *(const float4*)(xr + d0);
    unsigned lo = (unsigned)f2bf(xv.x) | ((unsigned)f2bf(xv.y) << 16);
    unsigned hi = (unsigned)f2bf(xv.z) | ((unsigned)f2bf(xv.w) << 16);
    *(unsigned*)(xbr + d0) = lo;
    *(unsigned*)(xbr + d0 + 2) = hi;
    const float xs[4] = {xv.x, xv.y, xv.z, xv.w};
#pragma unroll
    for (int jj = 0; jj < 4; ++jj) {
      const float4 w0 = *(const float4*)(Wr + (size_t)(d0 + jj) * 8);
      const float4 w1 = *(const float4*)(Wr + (size_t)(d0 + jj) * 8 + 4);
      p[0] += xs[jj] * w0.x; p[1] += xs[jj] * w0.y;
      p[2] += xs[jj] * w0.z; p[3] += xs[jj] * w0.w;
      p[4] += xs[jj] * w1.x; p[5] += xs[jj] * w1.y;
      p[6] += xs[jj] * w1.z; p[7] += xs[jj] * w1.w;
    }
  }
#pragma unroll
  for (int e = 0; e < 8; ++e) {
    float v = p[e];
#pragma unroll
    for (int off = 32; off > 0; off >>= 1) v += __shfl_xor(v, off, 64);
    p[e] = v;
  }
  constexpr float INV_TEMP = 0.36787944117144233f;  // 1/e
  float mx = -1e30f;
#pragma unroll
  for (int e = 0; e < 8; ++e) { p[e] *= INV_TEMP; mx = fmaxf(mx, p[e]); }
  float sum = 0.f;
#pragma unroll
  for (int e = 0; e < 8; ++e) { p[e] = __expf(p[e] - mx); sum += p[e]; }
  const float inv_sum = 1.f / sum;
#pragma unroll
  for (int e = 0; e < 8; ++e) p[e] *= inv_sum;
  // drop the 3 smallest probs (ties: drop higher index, matching top_k)
  unsigned sel = 0xFFu;
  for (int it = 0; it < 3; ++it) {
    float mn = 1e30f; int mi = 0;
#pragma unroll
    for (int e = 0; e < 8; ++e)
      if ((sel >> e) & 1u) { if (p[e] <= mn) { mn = p[e]; mi = e; } }
    sel &= ~(1u << mi);
  }
  float wsum = 0.f;
#pragma unroll
  for (int e = 0; e < 8; ++e) if ((sel >> e) & 1u) wsum += p[e];
  const float inv_w = 1.f / (wsum + 1e-8f);
  if (l == 0) {
#pragma unroll
    for (int e = 0; e < 8; ++e) {
      float v = ((sel >> e) & 1u) ? p[e] * inv_w : 0.f;
      Cw[(size_t)t * 8 + e] = (e < 4) ? v : -v;
    }
  }
}

// ------------- per-expert token compaction (sorted, deterministic) -------
__global__ __launch_bounds__(256) void build_idx(
    const float* __restrict__ Cw, int* __restrict__ idx, int* __restrict__ cnt) {
  const int e = blockIdx.x;           // 8 blocks
  const int tid = threadIdx.x;        // each thread scans 32 tokens
  const int t0 = tid * 32;
  int c = 0;
#pragma unroll
  for (int j = 0; j < 32; ++j)
    if (Cw[(size_t)(t0 + j) * 8 + e] != 0.f) ++c;
  __shared__ int s[256];
  s[tid] = c;
  __syncthreads();
  for (int off = 1; off < 256; off <<= 1) {
    int v = (tid >= off) ? s[tid - off] : 0;
    __syncthreads();
    s[tid] += v;
    __syncthreads();
  }
  int o = e * 8192 + s[tid] - c;      // exclusive prefix
  for (int j = 0; j < 32; ++j) {
    const int t = t0 + j;
    if (Cw[(size_t)t * 8 + e] != 0.f) idx[o++] = t;
  }
  if (tid == 255) cnt[e] = s[255];
}

// ------------- zero-fill inactive (token, expert) H' ranges -------------
__global__ __launch_bounds__(256) void zerofill(
    const float* __restrict__ Cw, u16* __restrict__ Hp, int p) {
  const int t = blockIdx.x * 4 + (threadIdx.x >> 6);   // 2048 blocks
  const int l = threadIdx.x & 63;
  bf16x8* rowp = (bf16x8*)(Hp + (size_t)t * 4096);
  const bf16x8 z = {0, 0, 0, 0, 0, 0, 0, 0};
#pragma unroll
  for (int el = 0; el < 4; ++el) {
    if (Cw[(size_t)t * 8 + p * 4 + el] == 0.f) {
      rowp[el * 128 + l] = z;
      rowp[el * 128 + 64 + l] = z;
    }
  }
}

// ------------- fused transpose + fp32->bf16 (64x64 tiles, 3 tensors) -----
// z 0-7: Wg slice z; z 8-15: Wu slice z-8; z 16-23: Wd slice z-16.
__global__ __launch_bounds__(256) void tcvt3_kernel(
    const float* __restrict__ Wg, const float* __restrict__ Wu,
    const float* __restrict__ Wd, u16* __restrict__ Wgt,
    u16* __restrict__ Wut, u16* __restrict__ Wdt) {
  __shared__ float tile[64][65];
  const int z = blockIdx.z;
  const int which = z >> 3, zs = z & 7;
  const float* in; u16* out; int R, C; long long ZO, CS;
  if (which == 0)      { in = Wg; out = Wgt; R = 2048; C = 1024; ZO = 2097152; CS = 2048; }
  else if (which == 1) { in = Wu; out = Wut; R = 2048; C = 1024; ZO = 2097152; CS = 2048; }
  else                 { in = Wd; out = Wdt; R = 1024; C = 2048; ZO = 1024;    CS = 8192; }
  const int r0 = blockIdx.y * 64, c0 = blockIdx.x * 64;
  if (r0 >= R || c0 >= C) return;
  const float* ib = in + (size_t)zs * R * C;
  const int tx = threadIdx.x, ty = threadIdx.y;  // 64 x 4
#pragma unroll
  for (int j = 0; j < 16; ++j)
    tile[ty + j * 4][tx] = ib[(size_t)(r0 + ty + j * 4) * C + c0 + tx];
  __syncthreads();
#pragma unroll
  for (int j = 0; j < 16; ++j)
    out[(size_t)zs * ZO + (size_t)(c0 + ty + j * 4) * CS + r0 + tx] =
        f2bf(tile[tx][ty + j * 4]);
}

// =========== 8-phase 256-wide GEMMs (T1+T2+T3+T4+T5 stack) ===========
// Stage unit = 16KB = 128 rows x 64 k bf16, 2 x global_load_lds(16B)/thread.
// Units/K-tile: {0:Bg/B0, 1:Bu/B1, 2:A0, 3:A1}; each staged >=1 trailing
// barrier after its last reader. T2 swizzle: LDS granule (row,c) holds global
// granule c^(row&7); readers XOR the same -> 2-way max aliasing (free).
// Next-tile B reads at ph3 occur after VMCNT+SBAR (all waves' t+1 units
// arrived) and after ph3's MFMA cluster (B regs dead) -> no extra registers.

// -------- GEMM1 (dual G/U, BM=256 BN=128, optional token-gather) --------
__global__ __launch_bounds__(512, 2) void gemm1_8p(
    const u16* __restrict__ Xb, const u16* __restrict__ Wgt,
    const u16* __restrict__ Wut, const float* __restrict__ Cw,
    u16* __restrict__ Hp, const int* __restrict__ idx,
    const int* __restrict__ cnt, int p) {
  extern __shared__ u16 lds[];  // 65536 u16 = 128KB: 2 buf x 4 units x 8192
  const int tid = threadIdx.x;
  const int l = tid & 63, w = tid >> 6;
  const int wr = w >> 2, wc = w & 3;      // 2(M) x 4(N) waves; per-wave 128x32
  const int lq = l >> 4, lr = l & 15;
  const int bid = blockIdx.x;             // 1024 blocks
  const int work = (bid & 7) * 128 + (bid >> 3);   // XCD chunk swizzle
  const int mtile = work & 31;
  const int en = work >> 5;
  const int el = en >> 3, nt = en & 7;
  const int e = p * 4 + el;
  const int cnt_e = idx ? cnt[e] : 8192;
  const int base = mtile * 256;
  if (base >= cnt_e) return;              // empty tile: exit before barriers
  const int* idxp = idx ? idx + (size_t)e * 8192 : nullptr;

  const u16* s0p = Wgt + (size_t)e * 2097152 + (size_t)nt * 128 * 2048;  // Bg
  const u16* s1p = Wut + (size_t)e * 2097152 + (size_t)nt * 128 * 2048;  // Bu

  const int lrow = tid >> 3;
  const int cgo = ((tid & 7) ^ (lrow & 7)) * 8;
  const int offB0 = lrow * 2048 + cgo;
  const int offB1 = offB0 + 64 * 2048;
  const int d0e = tid * 8, d1e = (512 + tid) * 8;

  auto gr = [&](int r) -> size_t {        // gathered A-row base (elements)
    const int rr = r < cnt_e ? r : cnt_e - 1;
    return (size_t)(idxp ? idxp[rr] : rr) * 2048 + cgo;
  };
  const size_t a20 = gr(base + lrow);
  const size_t a21 = gr(base + 64 + lrow);
  const size_t a30 = gr(base + 128 + lrow);
  const size_t a31 = gr(base + 192 + lrow);

  const int NT = 32;
  auto stageB = [&](int tt, const u16* srcb, int u) {
    if (tt >= NT) return;
    u16* dst = lds + (tt & 1) * 32768 + u * 8192;
    const int kt = tt * 64;
    gload16(srcb + offB0 + kt, dst + d0e);
    gload16(srcb + offB1 + kt, dst + d1e);
  };
  auto stageA = [&](int tt, size_t b0, size_t b1, int u) {
    if (tt >= NT) return;
    u16* dst = lds + (tt & 1) * 32768 + u * 8192;
    const int kt = tt * 64;
    gload16(Xb + b0 + kt, dst + d0e);
    gload16(Xb + b1 + kt, dst + d1e);
  };

  const int xr = lr & 7;
  const int x0 = (lq ^ xr) * 8;
  const int x1 = ((4 + lq) ^ xr) * 8;
  const int aB = (2 + wr) * 8192 + lr * 64;            // + mi*1024 + x
  const int gBo = (wc * 32 + lr) * 64;                 // Bg: + ni*1024 + x
  const int uBo = 8192 + (wc * 32 + lr) * 64;          // Bu

  bf16x8 a[8][2], bg[2][2], bu[2][2];
  f32x4 ag[8][2], au[8][2];
#pragma unroll
  for (int mi = 0; mi < 8; ++mi)
#pragma unroll
    for (int ni = 0; ni < 2; ++ni) {
      ag[mi][ni] = (f32x4){0.f, 0.f, 0.f, 0.f};
      au[mi][ni] = (f32x4){0.f, 0.f, 0.f, 0.f};
    }

  // prologue: tile0 units 0-3, tile1 units 0-2 (7 stages); vmcnt(6) -> t0 in
  stageB(0, s0p, 0); stageB(0, s1p, 1);
  stageA(0, a20, a21, 2); stageA(0, a30, a31, 3);
  stageB(1, s0p, 0); stageB(1, s1p, 1); stageA(1, a20, a21, 2);
  VMCNT6; SBAR;
  // prologue bg read for t=0 (buffer 0)
#pragma unroll
  for (int ni = 0; ni < 2; ++ni) {
    bg[ni][0] = *(const bf16x8*)&lds[gBo + ni * 1024 + x0];
    bg[ni][1] = *(const bf16x8*)&lds[gBo + ni * 1024 + x1];
  }

  for (int t = 0; t < NT; ++t) {
    const u16* Lb = lds + (t & 1) * 32768;
    // phase 0: read a[0-3] (8); stage A1(t+1); MFMA G m0-3
    {
#pragma unroll
      for (int mi = 0; mi < 4; ++mi) {
        a[mi][0] = *(const bf16x8*)&Lb[aB + mi * 1024 + x0];
        a[mi][1] = *(const bf16x8*)&Lb[aB + mi * 1024 + x1];
      }
      stageA(t + 1, a30, a31, 3);
      LGKM4; SBAR; LGKM0; SCHED0;
      PRIO1;
#pragma unroll
      for (int mi = 0; mi < 4; ++mi)
#pragma unroll
        for (int ni = 0; ni < 2; ++ni)
#pragma unroll
          for (int kk = 0; kk < 2; ++kk)
            ag[mi][ni] = MFMA16(a[mi][kk], bg[ni][kk], ag[mi][ni]);
      PRIO0; SCHED0; SBAR;
    }
    // phase 1: read bu (4); stage Bg(t+2); MFMA U m0-3
    {
#pragma unroll
      for (int ni = 0; ni < 2; ++ni) {
        bu[ni][0] = *(const bf16x8*)&Lb[uBo + ni * 1024 + x0];
        bu[ni][1] = *(const bf16x8*)&Lb[uBo + ni * 1024 + x1];
      }
      stageB(t + 2, s0p, 0);
      SBAR; LGKM0; SCHED0;
      PRIO1;
#pragma unroll
      for (int mi = 0; mi < 4; ++mi)
#pragma unroll
        for (int ni = 0; ni < 2; ++ni)
#pragma unroll
          for (int kk = 0; kk < 2; ++kk)
            au[mi][ni] = MFMA16(a[mi][kk], bu[ni][kk], au[mi][ni]);
      PRIO0; SCHED0; SBAR;
    }
    // phase 2: read a[4-7] (8); stage Bu(t+2); MFMA G m4-7
    {
#pragma unroll
      for (int mi = 4; mi < 8; ++mi) {
        a[mi][0] = *(const bf16x8*)&Lb[aB + mi * 1024 + x0];
        a[mi][1] = *(const bf16x8*)&Lb[aB + mi * 1024 + x1];
      }
      stageB(t + 2, s1p, 1);
      SBAR; LGKM0; SCHED0;
      PRIO1;
#pragma unroll
      for (int mi = 4; mi < 8; ++mi)
#pragma unroll
        for (int ni = 0; ni < 2; ++ni)
#pragma unroll
          for (int kk = 0; kk < 2; ++kk)
            ag[mi][ni] = MFMA16(a[mi][kk], bg[ni][kk], ag[mi][ni]);
      PRIO0; SCHED0; SBAR;
    }
    // phase 3: stage A0(t+2); vmcnt; MFMA U m4-7; then read bg(t+1) (4)
    {
      stageA(t + 2, a20, a21, 2);
      if (t < NT - 2) { VMCNT6; } else if (t == NT - 2) { VMCNT0; }
      SBAR; LGKM0; SCHED0;
      PRIO1;
#pragma unroll
      for (int mi = 4; mi < 8; ++mi)
#pragma unroll
        for (int ni = 0; ni < 2; ++ni)
#pragma unroll
          for (int kk = 0; kk < 2; ++kk)
            au[mi][ni] = MFMA16(a[mi][kk], bu[ni][kk], au[mi][ni]);
      PRIO0; SCHED0;
      {  // next-tile bg (t+1 buffer; harmless garbage at t==NT-1)
        const u16* Ln = lds + ((t + 1) & 1) * 32768;
#pragma unroll
        for (int ni = 0; ni < 2; ++ni) {
          bg[ni][0] = *(const bf16x8*)&Ln[gBo + ni * 1024 + x0];
          bg[ni][1] = *(const bf16x8*)&Ln[gBo + ni * 1024 + x1];
        }
      }
      SBAR;
    }
  }

  // epilogue: h = silu(g)*u*c -> bf16 into H'[orig_row, 4096]
#pragma unroll
  for (int mi = 0; mi < 8; ++mi) {
#pragma unroll
    for (int j = 0; j < 4; ++j) {
      const int rl = wr * 128 + mi * 16 + lq * 4 + j;
      const int grow = base + rl;
      if (grow < cnt_e) {
        const int orow = idxp ? idxp[grow] : grow;
        const float c = Cw[(size_t)orow * 8 + e];
#pragma unroll
        for (int ni = 0; ni < 2; ++ni) {
          const float g = ag[mi][ni][j], u = au[mi][ni][j];
          const float h = g * (1.f / (1.f + __expf(-g))) * u * c;
          Hp[(size_t)orow * 4096 + el * 1024 + nt * 128 + wc * 32 + ni * 16 + lr] =
              f2bf(h);
        }
      }
    }
  }
}

// ---------------- GEMM2 (BM=BN=256, out (+)= H'@Wdt; accum emits sqsum) --
__global__ __launch_bounds__(512, 2) void gemm2_8p(
    const u16* __restrict__ Hp, const u16* __restrict__ Wdt,
    float* __restrict__ out, float* __restrict__ part, int koff, int accum) {
  extern __shared__ u16 lds[];
  const int tid = threadIdx.x;
  const int l = tid & 63, w = tid >> 6;
  const int wr = w >> 2, wc = w & 3;      // per-wave 128x64
  const int lq = l >> 4, lr = l & 15;
  const int bid = blockIdx.x;             // 256 blocks
  const int work = (bid & 7) * 32 + (bid >> 3);
  const int mtile = work & 31, ntile = work >> 5;   // 32 x 8
  const u16* gA = Hp + (size_t)mtile * 256 * 4096;             // stride 4096
  const u16* gB = Wdt + (size_t)ntile * 256 * 8192 + koff;     // stride 8192
  const u16* s0p = gB;                       // B rows 0-127
  const u16* s1p = gB + (size_t)128 * 8192;  // B rows 128-255
  const u16* s2p = gA;                       // A rows 0-127
  const u16* s3p = gA + (size_t)128 * 4096;  // A rows 128-255
  const int NT = 64;                         // K = 4096

  const int row0 = tid >> 3,          cg0 = (tid & 7) ^ (row0 & 7);
  const int row1 = (512 + tid) >> 3,  cg1 = ((512 + tid) & 7) ^ (row1 & 7);
  const int offA0 = row0 * 4096 + cg0 * 8, offA1 = row1 * 4096 + cg1 * 8;
  const int offB0 = row0 * 8192 + cg0 * 8, offB1 = row1 * 8192 + cg1 * 8;
  const int d0e = tid * 8, d1e = (512 + tid) * 8;

  auto stageA = [&](int tt, const u16* srcb, int u) {
    if (tt >= NT) return;
    u16* dst = lds + (tt & 1) * 32768 + u * 8192;
    const int kt = tt * 64;
    gload16(srcb + (size_t)(offA0 + kt), dst + d0e);
    gload16(srcb + (size_t)(offA1 + kt), dst + d1e);
  };
  auto stageB = [&](int tt, const u16* srcb, int u) {
    if (tt >= NT) return;
    u16* dst = lds + (tt & 1) * 32768 + u * 8192;
    const int kt = tt * 64;
    gload16(srcb + (size_t)(offB0 + kt), dst + d0e);
    gload16(srcb + (size_t)(offB1 + kt), dst + d1e);
  };

  const int xr = lr & 7;
  const int x0 = (lq ^ xr) * 8;
  const int x1 = ((4 + lq) ^ xr) * 8;
  const int aB = (2 + wr) * 8192 + lr * 64;                    // + mi*1024
  const int bB = (wc >> 1) * 8192 + ((wc & 1) * 64 + lr) * 64; // + ni*1024

  bf16x8 a[8][2], b[4][2];
  f32x4 acc[8][4];
#pragma unroll
  for (int mi = 0; mi < 8; ++mi)
#pragma unroll
    for (int ni = 0; ni < 4; ++ni) acc[mi][ni] = (f32x4){0.f, 0.f, 0.f, 0.f};

  stageB(0, s0p, 0); stageB(0, s1p, 1); stageA(0, s2p, 2); stageA(0, s3p, 3);
  stageB(1, s0p, 0); stageB(1, s1p, 1); stageA(1, s2p, 2);
  VMCNT6; SBAR;
  // prologue b reads for t=0 (buffer 0)
#pragma unroll
  for (int ni = 0; ni < 2; ++ni) {
    b[ni][0] = *(const bf16x8*)&lds[bB + ni * 1024 + x0];
    b[ni][1] = *(const bf16x8*)&lds[bB + ni * 1024 + x1];
  }
  if (wc < 2) {
#pragma unroll
    for (int ni = 2; ni < 4; ++ni) {
      b[ni][0] = *(const bf16x8*)&lds[bB + ni * 1024 + x0];
      b[ni][1] = *(const bf16x8*)&lds[bB + ni * 1024 + x1];
    }
  }

  for (int t = 0; t < NT; ++t) {
    const u16* Lb = lds + (t & 1) * 32768;
    // phase 0: read a[0-3] (8); stage A1(t+1); MFMA m0-3 n0-1
    {
#pragma unroll
      for (int mi = 0; mi < 4; ++mi) {
        a[mi][0] = *(const bf16x8*)&Lb[aB + mi * 1024 + x0];
        a[mi][1] = *(const bf16x8*)&Lb[aB + mi * 1024 + x1];
      }
      stageA(t + 1, s3p, 3);
      LGKM4; SBAR; LGKM0; SCHED0;
      PRIO1;
#pragma unroll
      for (int mi = 0; mi < 4; ++mi)
#pragma unroll
        for (int ni = 0; ni < 2; ++ni)
#pragma unroll
          for (int kk = 0; kk < 2; ++kk)
            acc[mi][ni] = MFMA16(a[mi][kk], b[ni][kk], acc[mi][ni]);
      PRIO0; SCHED0; SBAR;
    }
    // phase 1: wc>=2 read b[2-3]; stage B0(t+2); MFMA m0-3 n2-3
    {
      if (wc >= 2) {
#pragma unroll
        for (int ni = 2; ni < 4; ++ni) {
          b[ni][0] = *(const bf16x8*)&Lb[bB + ni * 1024 + x0];
          b[ni][1] = *(const bf16x8*)&Lb[bB + ni * 1024 + x1];
        }
      }
      stageB(t + 2, s0p, 0);
      SBAR; LGKM0; SCHED0;
      PRIO1;
#pragma unroll
      for (int mi = 0; mi < 4; ++mi)
#pragma unroll
        for (int ni = 2; ni < 4; ++ni)
#pragma unroll
          for (int kk = 0; kk < 2; ++kk)
            acc[mi][ni] = MFMA16(a[mi][kk], b[ni][kk], acc[mi][ni]);
      PRIO0; SCHED0; SBAR;
    }
    // phase 2: read a[4-7] (8); stage B1(t+2); MFMA m4-7 n2-3
    {
#pragma unroll
      for (int mi = 4; mi < 8; ++mi) {
        a[mi][0] = *(const bf16x8*)&Lb[aB + mi * 1024 + x0];
        a[mi][1] = *(const bf16x8*)&Lb[aB + mi * 1024 + x1];
      }
      stageB(t + 2, s1p, 1);
      SBAR; LGKM0; SCHED0;
      PRIO1;
#pragma unroll
      for (int mi = 4; mi < 8; ++mi)
#pragma unroll
        for (int ni = 2; ni < 4; ++ni)
#pragma unroll
          for (int kk = 0; kk < 2; ++kk)
            acc[mi][ni] = MFMA16(a[mi][kk], b[ni][kk], acc[mi][ni]);
      PRIO0; SCHED0; SBAR;
    }
    // phase 3: stage A0(t+2); vmcnt; MFMA m4-7 n0-1; then read b(t+1)
    {
      stageA(t + 2, s2p, 2);
      if (t < NT - 2) { VMCNT6; } else if (t == NT - 2) { VMCNT0; }
      SBAR; LGKM0; SCHED0;
      PRIO1;
#pragma unroll
      for (int mi = 4; mi < 8; ++mi)
#pragma unroll
        for (int ni = 0; ni < 2; ++ni)
#pragma unroll
          for (int kk = 0; kk < 2; ++kk)
            acc[mi][ni] = MFMA16(a[mi][kk], b[ni][kk], acc[mi][ni]);
      PRIO0; SCHED0;
      {  // next-tile b01 (+wc<2: b23); garbage at t==NT-1, unused
        const u16* Ln = lds + ((t + 1) & 1) * 32768;
#pragma unroll
        for (int ni = 0; ni < 2; ++ni) {
          b[ni][0] = *(const bf16x8*)&Ln[bB + ni * 1024 + x0];
          b[ni][1] = *(const bf16x8*)&Ln[bB + ni * 1024 + x1];
        }
        if (wc < 2) {
#pragma unroll
          for (int ni = 2; ni < 4; ++ni) {
            b[ni][0] = *(const bf16x8*)&Ln[bB + ni * 1024 + x0];
            b[ni][1] = *(const bf16x8*)&Ln[bB + ni * 1024 + x1];
          }
        }
      }
      SBAR;
    }
  }

  float sq = 0.f;
#pragma unroll
  for (int mi = 0; mi < 8; ++mi)
#pragma unroll
    for (int ni = 0; ni < 4; ++ni)
#pragma unroll
      for (int j = 0; j < 4; ++j) {
        const int row = mtile * 256 + wr * 128 + mi * 16 + lq * 4 + j;
        const int col = ntile * 256 + wc * 64 + ni * 16 + lr;
        const size_t idx2 = (size_t)row * 2048 + col;
        float v = acc[mi][ni][j];
        if (accum) { v += out[idx2]; sq += v * v; }
        out[idx2] = v;
      }
  if (accum) {
#pragma unroll
    for (int off = 32; off > 0; off >>= 1) sq += __shfl_down(sq, off, 64);
    __syncthreads();                       // K-loop LDS no longer needed
    float* sm = (float*)lds;
    if (l == 0) sm[w] = sq;
    __syncthreads();
    if (tid == 0) {
      float tot = 0.f;
#pragma unroll
      for (int i = 0; i < 8; ++i) tot += sm[i];
      part[bid] = tot;
    }
  }
}

// ---------------- tension scalar final reduce ----------------
__global__ __launch_bounds__(256) void sqsum_final(
    const float* __restrict__ part, float* __restrict__ dst, int np, float scale) {
  float s = 0.f;
  for (int i = threadIdx.x; i < np; i += 256) s += part[i];
#pragma unroll
  for (int off = 32; off > 0; off >>= 1) s += __shfl_down(s, off, 64);
  __shared__ float ls[4];
  if ((threadIdx.x & 63) == 0) ls[threadIdx.x >> 6] = s;
  __syncthreads();
  if (threadIdx.x == 0) dst[0] = (ls[0] + ls[1] + ls[2] + ls[3]) * scale;
}

// ---------------- launch ----------------
extern "C" void kernel_launch(void* const* d_in, const int* in_sizes, int n_in,
                              void* d_out, int out_size, void* d_ws, size_t ws_size,
                              hipStream_t stream) {
  (void)in_sizes; (void)n_in; (void)out_size;
  const float* x  = (const float*)d_in[0];
  const float* Wr = (const float*)d_in[1];
  const float* Wg = (const float*)d_in[2];
  const float* Wu = (const float*)d_in[3];
  const float* Wd = (const float*)d_in[4];
  float* out = (float*)d_out;
  char* ws = (char*)d_ws;
  u16*   Xb   = (u16*)(ws);
  u16*   Wgt  = (u16*)(ws + 33554432);
  u16*   Wut  = (u16*)(ws + 67108864);
  u16*   Wdt  = (u16*)(ws + 100663296);
  u16*   Hp   = (u16*)(ws + 134217728);
  float* Cw   = (float*)(ws + 201326592);
  float* part = (float*)(ws + 201588736);
  const bool SPARSE = ws_size >= 201855008u;
  int* idxbuf = SPARSE ? (int*)(ws + 201592832) : nullptr;
  int* cntbuf = SPARSE ? (int*)(ws + 201854976) : nullptr;

  (void)hipFuncSetAttribute((const void*)gemm1_8p,
                            hipFuncAttributeMaxDynamicSharedMemorySize, 131072);
  (void)hipFuncSetAttribute((const void*)gemm2_8p,
                            hipFuncAttributeMaxDynamicSharedMemorySize, 131072);

  router_kernel<<<2048, 256, 0, stream>>>(x, Wr, Cw, Xb);
  if (SPARSE) build_idx<<<8, 256, 0, stream>>>(Cw, idxbuf, cntbuf);

  tcvt3_kernel<<<dim3(32, 32, 24), dim3(64, 4), 0, stream>>>(
      Wg, Wu, Wd, Wgt, Wut, Wdt);

  for (int p = 0; p < 2; ++p) {
    if (SPARSE) zerofill<<<2048, 256, 0, stream>>>(Cw, Hp, p);
    gemm1_8p<<<1024, 512, 131072, stream>>>(Xb, Wgt, Wut, Cw, Hp,
                                            idxbuf, cntbuf, p);
    gemm2_8p<<<256, 512, 131072, stream>>>(Hp, Wdt, out, part, p * 4096, p);
  }

  sqsum_final<<<1, 256, 0, stream>>>(part, out + 16777216, 256, 1.f / 16777216.f);
}